// Round 6
// baseline (1099.264 us; speedup 1.0000x reference)
//
#include <hip/hip_runtime.h>

#define BB 8
#define TT 128
#define EE 256
#define VV 8192
#define LL 5
#define NROWS (BB*TT)   // 1024

typedef __attribute__((ext_vector_type(8))) short bf16x8;
typedef __attribute__((ext_vector_type(4))) float f32x4;

__device__ inline ushort f2bf(float f) {
    union { float f; unsigned u; } c; c.f = f;
    unsigned u = c.u;
    return (ushort)((u + 0x7FFF + ((u >> 16) & 1)) >> 16);  // RNE
}

// lightweight grid barrier: device-scope atomics on a ws page (zeroed per call)
__device__ __forceinline__ void gridbar(int* bar, int idx) {
    __threadfence();                               // release: drain my stores, L2 wb
    __syncthreads();
    if (threadIdx.x == 0) {
        int* c = bar + idx * 16;                   // 64B per counter
        __hip_atomic_fetch_add(c, 1, __ATOMIC_RELAXED, __HIP_MEMORY_SCOPE_AGENT);
        while (__hip_atomic_load(c, __ATOMIC_RELAXED, __HIP_MEMORY_SCOPE_AGENT) < (int)gridDim.x)
            __builtin_amdgcn_s_sleep(2);
    }
    __syncthreads();
    __threadfence();                               // acquire: invalidate stale lines
}

// ================= mega kernel: prep + 5 transformer layers (cooperative, 256 blocks) =====
__global__ __launch_bounds__(256) void mega_kernel(
        const int* __restrict__ idxs, const float* __restrict__ emb, const float* __restrict__ pos,
        const float* __restrict__ Wq, const float* __restrict__ Wk,
        const float* __restrict__ Wv, const float* __restrict__ Wfc,
        const float* __restrict__ Wlm, const float* __restrict__ bfc,
        float* __restrict__ xa, float* __restrict__ xb,
        float* __restrict__ qt, float* __restrict__ kt, float* __restrict__ vt,
        ushort* __restrict__ WTs, ushort* __restrict__ WlmT, float* __restrict__ loss_cell,
        int* __restrict__ bar) {
    __shared__ __align__(16) ushort As[64*256];   // 32KB
    __shared__ __align__(16) ushort Bs[64*256];   // 32KB
    int tid = threadIdx.x, lane = tid & 63, w = tid >> 6;
    int blk = blockIdx.x;

    // ---------- phase 0: prep (1089 jobs) ----------
    for (int id = blk; id < 1089; id += 256) {
        if (id == 0) {
            if (tid == 0) *loss_cell = 0.f;
        } else if (id < 513) {
            ushort (*ts)[72] = (ushort(*)[72])As;
            int idw = id - 1;
            int v0 = (idw & 127) * 64, k0 = (idw >> 7) * 64;
            for (int kk = w; kk < 64; kk += 4)
                ts[lane][kk] = f2bf(Wlm[(size_t)(k0 + kk)*VV + v0 + lane]);
            __syncthreads();
            for (int vv = w; vv < 64; vv += 4)
                WlmT[(size_t)(v0 + vv)*EE + k0 + lane] = ts[vv][lane];
            __syncthreads();
        } else if (id < 833) {
            ushort (*ts)[72] = (ushort(*)[72])As;
            int idm = id - 513;
            int mat = idm >> 4, tile = idm & 15;
            int l = mat >> 2, type = mat & 3;
            const float* src = (type == 0 ? Wq : type == 1 ? Wk : type == 2 ? Wv : Wfc) + l*EE*EE;
            ushort* dst = WTs + mat*EE*EE;
            int i0 = (tile >> 2) * 64, o0 = (tile & 3) * 64;
            for (int ii = w; ii < 64; ii += 4)
                ts[lane][ii] = f2bf(src[(i0 + ii)*EE + o0 + lane]);
            __syncthreads();
            for (int oo = w; oo < 64; oo += 4)
                dst[(o0 + oo)*EE + i0 + lane] = ts[oo][lane];
            __syncthreads();
        } else {
            int row0 = (id - 833) * 4;
            for (int r = 0; r < 4; ++r) {
                int row = row0 + r;
                xa[row*EE + tid] = emb[(size_t)idxs[row]*EE + tid] + pos[(row & (TT-1))*EE + tid];
            }
        }
    }
    gridbar(bar, 0);

    // ---------- 5 layers ----------
    for (int l = 0; l < LL; ++l) {
        float* xi = (l & 1) ? xb : xa;
        float* xo = (l & 1) ? xa : xb;
        const ushort* WTl = WTs + (size_t)l*4*EE*EE;

        // ----- qkv: 192 jobs -----
        if (blk < 192) {
            int bx = blk % 12, by = blk / 12;
            int mat = bx >> 2;
            int c0 = (bx & 3) * 64;
            int r0 = by * 64;
            const ushort* WT = WTl + (size_t)mat*EE*EE;
            float* o = mat == 0 ? qt : (mat == 1 ? kt : vt);

            for (int rr = w; rr < 64; rr += 4) {
                float4 v = *(const float4*)&xi[(size_t)(r0 + rr)*EE + lane*4];
                ushort4 hh; hh.x = f2bf(v.x); hh.y = f2bf(v.y); hh.z = f2bf(v.z); hh.w = f2bf(v.w);
                *(ushort4*)&As[rr*256 + ((lane*4) ^ ((rr & 7) << 3))] = hh;
            }
            for (int it = 0; it < 8; ++it) {
                int c = w*16 + (lane >> 5) + 2*it;
                int k0i = (lane & 31) * 8;
                uint4 v = *(const uint4*)&WT[(size_t)(c0 + c)*EE + k0i];
                *(uint4*)&Bs[c*256 + (k0i ^ ((c & 7) << 3))] = v;
            }
            __syncthreads();
            f32x4 acc[4] = {};
            int rband = w*16 + (lane & 15);
            int kq = (lane >> 4) * 8;
            for (int ks = 0; ks < 8; ++ks) {
                int kk = ks*32 + kq;
                bf16x8 a = *(const bf16x8*)&As[rband*256 + (kk ^ ((rband & 7) << 3))];
                #pragma unroll
                for (int n = 0; n < 4; ++n) {
                    int c = n*16 + (lane & 15);
                    bf16x8 b = *(const bf16x8*)&Bs[c*256 + (kk ^ ((c & 7) << 3))];
                    acc[n] = __builtin_amdgcn_mfma_f32_16x16x32_bf16(a, b, acc[n], 0, 0, 0);
                }
            }
            int grow0 = r0 + w*16 + ((lane >> 4) << 2);
            int b = grow0 >> 7, t0 = grow0 & (TT-1);
            #pragma unroll
            for (int n = 0; n < 4; ++n) {
                int h = c0 + n*16 + (lane & 15);
                float4 vv = make_float4(acc[n][0], acc[n][1], acc[n][2], acc[n][3]);
                *(float4*)&o[((size_t)(b*EE + h))*TT + t0] = vv;
            }
        }
        gridbar(bar, 1 + l*3);

        // ----- attn: 8 heads per block, 32-thread group per head -----
        {
            float* fs = (float*)As;
            float* QS = fs;            // [8][128]
            float* KS = fs + 1024;
            float* VS = fs + 2048;     // later reused as out
            float* MS = fs + 3072;
            float* RV = fs + 4096;
            int g  = tid >> 5;
            int lg = tid & 31;
            int p  = blk*8 + g;        // bh index
            int base = p * TT;
            *(float4*)&QS[g*128 + lg*4] = *(const float4*)&qt[base + lg*4];
            *(float4*)&KS[g*128 + lg*4] = *(const float4*)&kt[base + lg*4];
            *(float4*)&VS[g*128 + lg*4] = *(const float4*)&vt[base + lg*4];
            __syncthreads();

            // phase 1: per-column stats over i >= j (4 cols per thread)
            int j0 = lg*4;
            float k0 = KS[g*128+j0+0], k1 = KS[g*128+j0+1];
            float k2 = KS[g*128+j0+2], k3 = KS[g*128+j0+3];
            float m0=-INFINITY, m1=-INFINITY, m2=-INFINITY, m3=-INFINITY;
            for (int i = j0; i < TT; ++i) {
                float qi = QS[g*128+i];
                m0 = fmaxf(m0, qi*k0);
                m1 = (i >= j0+1) ? fmaxf(m1, qi*k1) : m1;
                m2 = (i >= j0+2) ? fmaxf(m2, qi*k2) : m2;
                m3 = (i >= j0+3) ? fmaxf(m3, qi*k3) : m3;
            }
            float z0=0.f, z1=0.f, z2=0.f, z3=0.f;
            for (int i = j0; i < TT; ++i) {
                float qi = QS[g*128+i];
                z0 += __expf(qi*k0 - m0);
                z1 += (i >= j0+1) ? __expf(qi*k1 - m1) : 0.f;
                z2 += (i >= j0+2) ? __expf(qi*k2 - m2) : 0.f;
                z3 += (i >= j0+3) ? __expf(qi*k3 - m3) : 0.f;
            }
            MS[g*128+j0+0] = m0; MS[g*128+j0+1] = m1;
            MS[g*128+j0+2] = m2; MS[g*128+j0+3] = m3;
            RV[g*128+j0+0] = VS[g*128+j0+0] / z0;
            RV[g*128+j0+1] = VS[g*128+j0+1] / z1;
            RV[g*128+j0+2] = VS[g*128+j0+2] / z2;
            RV[g*128+j0+3] = VS[g*128+j0+3] / z3;
            __syncthreads();

            // phase 2: per-row out_i = sum_{j<=i} exp(q_i k_j - m_j) * rv_j (4 rows per thread)
            int i0 = lg*4;
            float q0 = QS[g*128+i0+0], q1 = QS[g*128+i0+1];
            float q2 = QS[g*128+i0+2], q3 = QS[g*128+i0+3];
            float a0=0.f, a1=0.f, a2=0.f, a3=0.f;
            for (int j = 0; j <= i0+3; ++j) {
                float kj = KS[g*128+j], mj = MS[g*128+j], rj = RV[g*128+j];
                float e0 = __expf(q0*kj - mj) * rj;
                float e1 = __expf(q1*kj - mj) * rj;
                float e2 = __expf(q2*kj - mj) * rj;
                float e3 = __expf(q3*kj - mj) * rj;
                a0 += (j <= i0+0) ? e0 : 0.f;
                a1 += (j <= i0+1) ? e1 : 0.f;
                a2 += (j <= i0+2) ? e2 : 0.f;
                a3 += j <= i0+3 ? e3 : 0.f;
            }
            VS[g*128+i0+0] = a0; VS[g*128+i0+1] = a1;
            VS[g*128+i0+2] = a2; VS[g*128+i0+3] = a3;
            __syncthreads();

            // coalesced RMW of x: block covers batch b, cols h0..h0+7, rows 0..127
            int row = tid >> 1, c4 = (tid & 1)*4;
            int b = blk >> 5, h0 = (blk & 31)*8;
            size_t gx = (size_t)(b*TT + row)*EE + h0 + c4;
            float4 xv = *(float4*)&xi[gx];
            xv.x += VS[(c4+0)*128 + row];
            xv.y += VS[(c4+1)*128 + row];
            xv.z += VS[(c4+2)*128 + row];
            xv.w += VS[(c4+3)*128 + row];
            *(float4*)&xi[gx] = xv;
        }
        gridbar(bar, 2 + l*3);

        // ----- fc: 64 jobs -----
        if (blk < 64) {
            const ushort* WT = WTl + (size_t)3*EE*EE;
            int c0 = (blk & 3) * 64;
            int r0 = (blk >> 2) * 64;
            for (int rr = w; rr < 64; rr += 4) {
                float4 v = *(const float4*)&xi[(size_t)(r0 + rr)*EE + lane*4];
                ushort4 hh; hh.x = f2bf(v.x); hh.y = f2bf(v.y); hh.z = f2bf(v.z); hh.w = f2bf(v.w);
                *(ushort4*)&As[rr*256 + ((lane*4) ^ ((rr & 7) << 3))] = hh;
            }
            for (int it = 0; it < 8; ++it) {
                int c = w*16 + (lane >> 5) + 2*it;
                int k0i = (lane & 31) * 8;
                uint4 v = *(const uint4*)&WT[(size_t)(c0 + c)*EE + k0i];
                *(uint4*)&Bs[c*256 + (k0i ^ ((c & 7) << 3))] = v;
            }
            __syncthreads();
            f32x4 acc[4] = {};
            int rband = w*16 + (lane & 15);
            int kq = (lane >> 4) * 8;
            for (int ks = 0; ks < 8; ++ks) {
                int kk = ks*32 + kq;
                bf16x8 a = *(const bf16x8*)&As[rband*256 + (kk ^ ((rband & 7) << 3))];
                #pragma unroll
                for (int n = 0; n < 4; ++n) {
                    int c = n*16 + (lane & 15);
                    bf16x8 b = *(const bf16x8*)&Bs[c*256 + (kk ^ ((c & 7) << 3))];
                    acc[n] = __builtin_amdgcn_mfma_f32_16x16x32_bf16(a, b, acc[n], 0, 0, 0);
                }
            }
            int grow0 = r0 + w*16 + ((lane >> 4) << 2);
            #pragma unroll
            for (int n = 0; n < 4; ++n) {
                int col = c0 + n*16 + (lane & 15);
                float bias = bfc[l*EE + col];
                #pragma unroll
                for (int j = 0; j < 4; ++j) {
                    size_t idx = (size_t)(grow0 + j)*EE + col;
                    xo[idx] = xi[idx] + fmaxf(acc[n][j] + bias, 0.f);
                }
            }
        }
        if (l < LL-1) gridbar(bar, 3 + l*3);
    }
}

// ---------------- logits = x @ Wlm + blm (MFMA) + fused per-(row,64col) softmax partials
__global__ __launch_bounds__(256) void lm_mfma_kernel(
        const float* __restrict__ x, const ushort* __restrict__ WlmT,
        const float* __restrict__ blm, float* __restrict__ out,
        float* __restrict__ pm, float* __restrict__ pz) {
    __shared__ __align__(16) ushort As[64*256];
    __shared__ __align__(16) ushort Bs[64*256];
    int tid = threadIdx.x;
    int lane = tid & 63, w = tid >> 6;
    int c0 = blockIdx.x * 64;
    int r0 = blockIdx.y * 64;

    for (int rr = w; rr < 64; rr += 4) {
        float4 v = *(const float4*)&x[(size_t)(r0 + rr)*EE + lane*4];
        ushort4 hh; hh.x = f2bf(v.x); hh.y = f2bf(v.y); hh.z = f2bf(v.z); hh.w = f2bf(v.w);
        *(ushort4*)&As[rr*256 + ((lane*4) ^ ((rr & 7) << 3))] = hh;
    }
    for (int it = 0; it < 8; ++it) {
        int c = w*16 + (lane >> 5) + 2*it;
        int k0i = (lane & 31) * 8;
        uint4 v = *(const uint4*)&WlmT[(size_t)(c0 + c)*EE + k0i];
        *(uint4*)&Bs[c*256 + (k0i ^ ((c & 7) << 3))] = v;
    }
    __syncthreads();

    f32x4 acc[4] = {};
    int rband = w*16 + (lane & 15);
    int kq = (lane >> 4) * 8;
    for (int ks = 0; ks < 8; ++ks) {
        int kk = ks*32 + kq;
        bf16x8 a = *(const bf16x8*)&As[rband*256 + (kk ^ ((rband & 7) << 3))];
        #pragma unroll
        for (int n = 0; n < 4; ++n) {
            int c = n*16 + (lane & 15);
            bf16x8 b = *(const bf16x8*)&Bs[c*256 + (kk ^ ((c & 7) << 3))];
            acc[n] = __builtin_amdgcn_mfma_f32_16x16x32_bf16(a, b, acc[n], 0, 0, 0);
        }
    }

    float bias[4];
    #pragma unroll
    for (int n = 0; n < 4; ++n) bias[n] = blm[c0 + n*16 + (lane & 15)];
    int rowg = r0 + w*16 + (lane >> 4)*4;
    #pragma unroll
    for (int j = 0; j < 4; ++j) {
        float vals[4];
        float vmax = -INFINITY;
        #pragma unroll
        for (int n = 0; n < 4; ++n) {
            vals[n] = acc[n][j] + bias[n];
            out[(size_t)(rowg + j)*VV + c0 + n*16 + (lane & 15)] = vals[n];
            vmax = fmaxf(vmax, vals[n]);
        }
        #pragma unroll
        for (int m = 1; m <= 8; m <<= 1) vmax = fmaxf(vmax, __shfl_xor(vmax, m));
        float z = 0.f;
        #pragma unroll
        for (int n = 0; n < 4; ++n) z += __expf(vals[n] - vmax);
        #pragma unroll
        for (int m = 1; m <= 8; m <<= 1) z += __shfl_xor(z, m);
        if ((lane & 15) == 0) {
            pm[(size_t)(rowg + j)*128 + blockIdx.x] = vmax;
            pz[(size_t)(rowg + j)*128 + blockIdx.x] = z;
        }
    }
}

// ---------------- per-row loss from partials, atomicAdd mean into pre-zeroed loss cell
__global__ void loss_kernel(const float* __restrict__ pm, const float* __restrict__ pz,
                            const float* __restrict__ logits, const int* __restrict__ targets,
                            float* __restrict__ out_last) {
    int r = blockIdx.x;
    int t = threadIdx.x;             // 128
    __shared__ float sm[128], sz[128];
    float m = pm[(size_t)r*128 + t];
    float z = pz[(size_t)r*128 + t];
    sm[t] = m; __syncthreads();
    for (int s = 64; s > 0; s >>= 1) {
        if (t < s) sm[t] = fmaxf(sm[t], sm[t + s]);
        __syncthreads();
    }
    float M = sm[0];
    sz[t] = z * __expf(m - M); __syncthreads();
    for (int s = 64; s > 0; s >>= 1) {
        if (t < s) sz[t] += sz[t + s];
        __syncthreads();
    }
    if (t == 0) {
        float lse = M + logf(sz[0]);
        atomicAdd(out_last, (lse - logits[(size_t)r*VV + targets[r]]) * (1.0f / NROWS));
    }
}

extern "C" void kernel_launch(void* const* d_in, const int* in_sizes, int n_in,
                              void* d_out, int out_size, void* d_ws, size_t ws_size,
                              hipStream_t stream) {
    const int*   idxs    = (const int*)d_in[0];
    const int*   targets = (const int*)d_in[1];
    const float* emb     = (const float*)d_in[2];
    const float* pos     = (const float*)d_in[3];
    const float* Wq      = (const float*)d_in[4];
    const float* Wk      = (const float*)d_in[5];
    const float* Wv      = (const float*)d_in[6];
    const float* Wfc     = (const float*)d_in[7];
    const float* bfc     = (const float*)d_in[8];
    const float* Wlm     = (const float*)d_in[9];
    const float* blm     = (const float*)d_in[10];
    float* out = (float*)d_out;
    float* loss_cell = out + (size_t)NROWS * VV;

    float* ws = (float*)d_ws;
    float*  xa   = ws;                       // [1024,256]
    float*  xb   = xa + NROWS*EE;
    float*  qt   = xb + NROWS*EE;            // [B,H,T]
    float*  kt   = qt + NROWS*EE;
    float*  vt   = kt + NROWS*EE;
    float*  pm   = vt + NROWS*EE;            // [1024,128]
    float*  pz   = pm + NROWS*128;
    ushort* WTs  = (ushort*)(pz + NROWS*128);   // 20 * 256*256 bf16
    ushort* WlmT = WTs + 20*EE*EE;              // 8192*256 bf16
    int*    bar  = (int*)(WlmT + (size_t)VV*EE);  // 15 counters * 64B

    hipMemsetAsync(bar, 0, 15*16*sizeof(int), stream);

    void* kargs[] = {
        (void*)&idxs, (void*)&emb, (void*)&pos,
        (void*)&Wq, (void*)&Wk, (void*)&Wv, (void*)&Wfc,
        (void*)&Wlm, (void*)&bfc,
        (void*)&xa, (void*)&xb, (void*)&qt, (void*)&kt, (void*)&vt,
        (void*)&WTs, (void*)&WlmT, (void*)&loss_cell, (void*)&bar
    };
    hipLaunchCooperativeKernel((const void*)mega_kernel, dim3(256), dim3(256), kargs, 0, stream);

    lm_mfma_kernel<<<dim3(VV/64, NROWS/64), 256, 0, stream>>>(xb, WlmT, blm, out, pm, pz);
    loss_kernel<<<NROWS, 128, 0, stream>>>(pm, pz, out, targets, loss_cell);
}

// Round 7
// 317.453 us; speedup vs baseline: 3.4628x; 3.4628x over previous
//
#include <hip/hip_runtime.h>

#define BB 8
#define TT 128
#define EE 256
#define VV 8192
#define LL 5
#define NROWS (BB*TT)   // 1024

typedef __attribute__((ext_vector_type(8))) short bf16x8;
typedef __attribute__((ext_vector_type(4))) float f32x4;

__device__ inline ushort f2bf(float f) {
    union { float f; unsigned u; } c; c.f = f;
    unsigned u = c.u;
    return (ushort)((u + 0x7FFF + ((u >> 16) & 1)) >> 16);  // RNE
}
__device__ inline float bf2f(ushort u) {
    union { unsigned u; float f; } c; c.u = ((unsigned)u) << 16;
    return c.f;
}

// ---------------- prep: zero loss+counters, WlmT, weight transposes, embedding ----------
__global__ __launch_bounds__(256) void prep_kernel(
        const int* __restrict__ idxs, const float* __restrict__ emb, const float* __restrict__ pos,
        const float* __restrict__ Wq, const float* __restrict__ Wk,
        const float* __restrict__ Wv, const float* __restrict__ Wfc,
        const float* __restrict__ Wlm,
        float* __restrict__ x0, ushort* __restrict__ WTs, ushort* __restrict__ WlmT,
        float* __restrict__ loss_cell, int* __restrict__ row_done) {
    int id = blockIdx.x;
    if (id == 0) {
        if (threadIdx.x == 0) *loss_cell = 0.f;
        if (threadIdx.x < 16) row_done[threadIdx.x] = 0;
        return;
    }
    if (id < 513) {
        __shared__ ushort ts[64][72];
        int idw = id - 1;
        int v0 = (idw & 127) * 64, k0 = (idw >> 7) * 64;
        int lane = threadIdx.x & 63, w = threadIdx.x >> 6;
        for (int kk = w; kk < 64; kk += 4)
            ts[lane][kk] = f2bf(Wlm[(size_t)(k0 + kk)*VV + v0 + lane]);
        __syncthreads();
        for (int vv = w; vv < 64; vv += 4)
            WlmT[(size_t)(v0 + vv)*EE + k0 + lane] = ts[vv][lane];
        return;
    }
    if (id < 833) {
        __shared__ ushort ts[64][72];
        int idm = id - 513;
        int mat = idm >> 4, tile = idm & 15;
        int l = mat >> 2, type = mat & 3;
        const float* src = (type == 0 ? Wq : type == 1 ? Wk : type == 2 ? Wv : Wfc) + l*EE*EE;
        ushort* dst = WTs + mat*EE*EE;
        int i0 = (tile >> 2) * 64, o0 = (tile & 3) * 64;
        int lane = threadIdx.x & 63, w = threadIdx.x >> 6;
        for (int ii = w; ii < 64; ii += 4)
            ts[lane][ii] = f2bf(src[(i0 + ii)*EE + o0 + lane]);
        __syncthreads();
        for (int oo = w; oo < 64; oo += 4)
            dst[(o0 + oo)*EE + i0 + lane] = ts[oo][lane];
        return;
    }
    int h = threadIdx.x;
    int row0 = (id - 833) * 4;
    for (int r = 0; r < 4; ++r) {
        int row = row0 + r;
        x0[row*EE + h] = emb[(size_t)idxs[row]*EE + h] + pos[(row & (TT-1))*EE + h];
    }
}

// ---------------- q,k,v = x @ W (3 GEMMs along grid.x), transposed f32 stores [B,H,T]
__global__ __launch_bounds__(256) void qkv_mfma(
        const float* __restrict__ xin, const ushort* __restrict__ WTl,
        float* __restrict__ qt, float* __restrict__ kt, float* __restrict__ vt) {
    __shared__ __align__(16) ushort As[64*256];
    __shared__ __align__(16) ushort Bs[64*256];
    int tid = threadIdx.x, lane = tid & 63, w = tid >> 6;
    int mat = blockIdx.x >> 2;
    int c0 = (blockIdx.x & 3) * 64;
    int r0 = blockIdx.y * 64;
    const ushort* WT = WTl + (size_t)mat*EE*EE;
    float* o = mat == 0 ? qt : (mat == 1 ? kt : vt);

    for (int rr = w; rr < 64; rr += 4) {
        float4 v = *(const float4*)&xin[(size_t)(r0 + rr)*EE + lane*4];
        ushort4 hh; hh.x = f2bf(v.x); hh.y = f2bf(v.y); hh.z = f2bf(v.z); hh.w = f2bf(v.w);
        *(ushort4*)&As[rr*256 + ((lane*4) ^ ((rr & 7) << 3))] = hh;
    }
    for (int it = 0; it < 8; ++it) {
        int c = w*16 + (lane >> 5) + 2*it;
        int k0i = (lane & 31) * 8;
        uint4 v = *(const uint4*)&WT[(size_t)(c0 + c)*EE + k0i];
        *(uint4*)&Bs[c*256 + (k0i ^ ((c & 7) << 3))] = v;
    }
    __syncthreads();
    f32x4 acc[4] = {};
    int rband = w*16 + (lane & 15);
    int kq = (lane >> 4) * 8;
    for (int ks = 0; ks < 8; ++ks) {
        int kk = ks*32 + kq;
        bf16x8 a = *(const bf16x8*)&As[rband*256 + (kk ^ ((rband & 7) << 3))];
        #pragma unroll
        for (int n = 0; n < 4; ++n) {
            int c = n*16 + (lane & 15);
            bf16x8 b = *(const bf16x8*)&Bs[c*256 + (kk ^ ((c & 7) << 3))];
            acc[n] = __builtin_amdgcn_mfma_f32_16x16x32_bf16(a, b, acc[n], 0, 0, 0);
        }
    }
    int grow0 = r0 + w*16 + ((lane >> 4) << 2);
    int b = grow0 >> 7, t0 = grow0 & (TT-1);
    #pragma unroll
    for (int n = 0; n < 4; ++n) {
        int h = c0 + n*16 + (lane & 15);
        float4 vv = make_float4(acc[n][0], acc[n][1], acc[n][2], acc[n][3]);
        *(float4*)&o[((size_t)(b*EE + h))*TT + t0] = vv;
    }
}

// ---------------- attn v2: 8 heads/block, 32-lane group per head, grid 256
__global__ __launch_bounds__(256) void attn_kernel(
        const float* __restrict__ qt, const float* __restrict__ kt,
        const float* __restrict__ vt, float* __restrict__ x) {
    __shared__ __align__(16) float QS[8*128], KS[8*128], VS[8*128], MS[8*128], RV[8*128];
    int tid = threadIdx.x;
    int g = tid >> 5, lg = tid & 31;
    int blk = blockIdx.x;
    int p = blk*8 + g;               // bh index
    int base = p * TT;
    *(float4*)&QS[g*128 + lg*4] = *(const float4*)&qt[base + lg*4];
    *(float4*)&KS[g*128 + lg*4] = *(const float4*)&kt[base + lg*4];
    *(float4*)&VS[g*128 + lg*4] = *(const float4*)&vt[base + lg*4];
    __syncthreads();

    // phase 1: per-column softmax stats over i >= j (4 cols per lane)
    int j0 = lg*4;
    float4 kv = *(float4*)&KS[g*128 + j0];
    float m0=-INFINITY, m1=-INFINITY, m2=-INFINITY, m3=-INFINITY;
    for (int i = j0; i < TT; ++i) {
        float qi = QS[g*128+i];
        m0 = fmaxf(m0, qi*kv.x);
        m1 = (i >= j0+1) ? fmaxf(m1, qi*kv.y) : m1;
        m2 = (i >= j0+2) ? fmaxf(m2, qi*kv.z) : m2;
        m3 = (i >= j0+3) ? fmaxf(m3, qi*kv.w) : m3;
    }
    float z0=0.f, z1=0.f, z2=0.f, z3=0.f;
    for (int i = j0; i < TT; ++i) {
        float qi = QS[g*128+i];
        z0 += __expf(qi*kv.x - m0);
        z1 += (i >= j0+1) ? __expf(qi*kv.y - m1) : 0.f;
        z2 += (i >= j0+2) ? __expf(qi*kv.z - m2) : 0.f;
        z3 += (i >= j0+3) ? __expf(qi*kv.w - m3) : 0.f;
    }
    *(float4*)&MS[g*128 + j0] = make_float4(m0, m1, m2, m3);
    float4 vv = *(float4*)&VS[g*128 + j0];
    *(float4*)&RV[g*128 + j0] = make_float4(vv.x/z0, vv.y/z1, vv.z/z2, vv.w/z3);
    __syncthreads();

    // phase 2: per-row out_i = sum_{j<=i} exp(q_i k_j - m_j) * rv_j (4 rows per lane)
    int i0 = lg*4;
    float4 qv = *(float4*)&QS[g*128 + i0];
    float a0=0.f, a1=0.f, a2=0.f, a3=0.f;
    for (int j = 0; j <= i0+3; ++j) {
        float kj = KS[g*128+j], mj = MS[g*128+j], rj = RV[g*128+j];
        float e0 = __expf(qv.x*kj - mj) * rj;
        float e1 = __expf(qv.y*kj - mj) * rj;
        float e2 = __expf(qv.z*kj - mj) * rj;
        float e3 = __expf(qv.w*kj - mj) * rj;
        a0 += (j <= i0+0) ? e0 : 0.f;
        a1 += (j <= i0+1) ? e1 : 0.f;
        a2 += (j <= i0+2) ? e2 : 0.f;
        a3 += (j <= i0+3) ? e3 : 0.f;
    }
    __syncthreads();
    *(float4*)&VS[g*128 + i0] = make_float4(a0, a1, a2, a3);
    __syncthreads();

    // coalesced RMW: block covers batch b, cols h0..h0+7, rows 0..127
    int row = tid >> 1, c4 = (tid & 1)*4;
    int b = blk >> 5, h0 = (blk & 31)*8;
    size_t gx = (size_t)(b*TT + row)*EE + h0 + c4;
    float4 xv = *(float4*)&x[gx];
    xv.x += VS[(c4+0)*128 + row];
    xv.y += VS[(c4+1)*128 + row];
    xv.z += VS[(c4+2)*128 + row];
    xv.w += VS[(c4+3)*128 + row];
    *(float4*)&x[gx] = xv;
}

// ---------------- xout = xin + relu(xin @ Wfc + bfc)
__global__ __launch_bounds__(256) void fc_mfma(
        const float* __restrict__ xin, const ushort* __restrict__ WT,
        const float* __restrict__ bfc, float* __restrict__ xout) {
    __shared__ __align__(16) ushort As[64*256];
    __shared__ __align__(16) ushort Bs[64*256];
    int tid = threadIdx.x, lane = tid & 63, w = tid >> 6;
    int c0 = blockIdx.x * 64;
    int r0 = blockIdx.y * 64;

    for (int rr = w; rr < 64; rr += 4) {
        float4 v = *(const float4*)&xin[(size_t)(r0 + rr)*EE + lane*4];
        ushort4 hh; hh.x = f2bf(v.x); hh.y = f2bf(v.y); hh.z = f2bf(v.z); hh.w = f2bf(v.w);
        *(ushort4*)&As[rr*256 + ((lane*4) ^ ((rr & 7) << 3))] = hh;
    }
    for (int it = 0; it < 8; ++it) {
        int c = w*16 + (lane >> 5) + 2*it;
        int k0i = (lane & 31) * 8;
        uint4 v = *(const uint4*)&WT[(size_t)(c0 + c)*EE + k0i];
        *(uint4*)&Bs[c*256 + (k0i ^ ((c & 7) << 3))] = v;
    }
    __syncthreads();
    f32x4 acc[4] = {};
    int rband = w*16 + (lane & 15);
    int kq = (lane >> 4) * 8;
    for (int ks = 0; ks < 8; ++ks) {
        int kk = ks*32 + kq;
        bf16x8 a = *(const bf16x8*)&As[rband*256 + (kk ^ ((rband & 7) << 3))];
        #pragma unroll
        for (int n = 0; n < 4; ++n) {
            int c = n*16 + (lane & 15);
            bf16x8 b = *(const bf16x8*)&Bs[c*256 + (kk ^ ((c & 7) << 3))];
            acc[n] = __builtin_amdgcn_mfma_f32_16x16x32_bf16(a, b, acc[n], 0, 0, 0);
        }
    }
    int grow0 = r0 + w*16 + ((lane >> 4) << 2);
    #pragma unroll
    for (int n = 0; n < 4; ++n) {
        int col = c0 + n*16 + (lane & 15);
        float bias = bfc[col];
        #pragma unroll
        for (int j = 0; j < 4; ++j) {
            size_t idx = (size_t)(grow0 + j)*EE + col;
            xout[idx] = xin[idx] + fmaxf(acc[n][j] + bias, 0.f);
        }
    }
}

// ---------------- lm: logits + softmax partials + last-arriver loss reduction
__global__ __launch_bounds__(256) void lm_loss_kernel(
        const float* __restrict__ x, const ushort* __restrict__ WlmT,
        const float* __restrict__ blm, const int* __restrict__ targets,
        float* __restrict__ out, float* __restrict__ pm, float* __restrict__ pz,
        int* __restrict__ row_done, float* __restrict__ loss_cell) {
    __shared__ __align__(16) ushort As[64*256];
    __shared__ __align__(16) ushort Bs[64*256];
    __shared__ int oldc;
    int tid = threadIdx.x;
    int lane = tid & 63, w = tid >> 6;
    int c0 = blockIdx.x * 64;
    int r0 = blockIdx.y * 64;

    for (int rr = w; rr < 64; rr += 4) {
        float4 v = *(const float4*)&x[(size_t)(r0 + rr)*EE + lane*4];
        ushort4 hh; hh.x = f2bf(v.x); hh.y = f2bf(v.y); hh.z = f2bf(v.z); hh.w = f2bf(v.w);
        *(ushort4*)&As[rr*256 + ((lane*4) ^ ((rr & 7) << 3))] = hh;
    }
    for (int it = 0; it < 8; ++it) {
        int c = w*16 + (lane >> 5) + 2*it;
        int k0i = (lane & 31) * 8;
        uint4 v = *(const uint4*)&WlmT[(size_t)(c0 + c)*EE + k0i];
        *(uint4*)&Bs[c*256 + (k0i ^ ((c & 7) << 3))] = v;
    }
    __syncthreads();

    f32x4 acc[4] = {};
    int rband = w*16 + (lane & 15);
    int kq = (lane >> 4) * 8;
    for (int ks = 0; ks < 8; ++ks) {
        int kk = ks*32 + kq;
        bf16x8 a = *(const bf16x8*)&As[rband*256 + (kk ^ ((rband & 7) << 3))];
        #pragma unroll
        for (int n = 0; n < 4; ++n) {
            int c = n*16 + (lane & 15);
            bf16x8 b = *(const bf16x8*)&Bs[c*256 + (kk ^ ((c & 7) << 3))];
            acc[n] = __builtin_amdgcn_mfma_f32_16x16x32_bf16(a, b, acc[n], 0, 0, 0);
        }
    }

    float bias[4];
    #pragma unroll
    for (int n = 0; n < 4; ++n) bias[n] = blm[c0 + n*16 + (lane & 15)];
    int rowg = r0 + w*16 + (lane >> 4)*4;
    #pragma unroll
    for (int j = 0; j < 4; ++j) {
        float vals[4];
        float vmax = -INFINITY;
        #pragma unroll
        for (int n = 0; n < 4; ++n) {
            vals[n] = acc[n][j] + bias[n];
            out[(size_t)(rowg + j)*VV + c0 + n*16 + (lane & 15)] = vals[n];
            vmax = fmaxf(vmax, vals[n]);
        }
        #pragma unroll
        for (int m = 1; m <= 8; m <<= 1) vmax = fmaxf(vmax, __shfl_xor(vmax, m));
        float z = 0.f;
        #pragma unroll
        for (int n = 0; n < 4; ++n) z += __expf(vals[n] - vmax);
        #pragma unroll
        for (int m = 1; m <= 8; m <<= 1) z += __shfl_xor(z, m);
        if ((lane & 15) == 0) {
            // write-through to coherence point: visible to other XCDs without L2 flush
            __hip_atomic_store(&pm[(size_t)(rowg + j)*128 + blockIdx.x], vmax,
                               __ATOMIC_RELAXED, __HIP_MEMORY_SCOPE_AGENT);
            __hip_atomic_store(&pz[(size_t)(rowg + j)*128 + blockIdx.x], z,
                               __ATOMIC_RELAXED, __HIP_MEMORY_SCOPE_AGENT);
        }
    }

    // arrival: all stores drained, then count up; 128th block reduces the row-group
    __builtin_amdgcn_s_waitcnt(0);
    __syncthreads();
    if (tid == 0)
        oldc = __hip_atomic_fetch_add(&row_done[blockIdx.y], 1,
                                      __ATOMIC_RELAXED, __HIP_MEMORY_SCOPE_AGENT);
    __syncthreads();
    if (oldc != 127) return;

    // reduction: 64 rows x 4 threads; each thread merges 32 (m,z) partials online
    int rr = tid >> 2, q = tid & 3;
    int row = r0 + rr;
    float m = -INFINITY, z = 0.f;
    for (int i = 0; i < 32; ++i) {
        float pmv = __hip_atomic_load(&pm[(size_t)row*128 + q*32 + i],
                                      __ATOMIC_RELAXED, __HIP_MEMORY_SCOPE_AGENT);
        float pzv = __hip_atomic_load(&pz[(size_t)row*128 + q*32 + i],
                                      __ATOMIC_RELAXED, __HIP_MEMORY_SCOPE_AGENT);
        float nm = fmaxf(m, pmv);
        z = z * __expf(m - nm) + pzv * __expf(pmv - nm);
        m = nm;
    }
    #pragma unroll
    for (int msk = 1; msk <= 2; msk <<= 1) {
        float om = __shfl_xor(m, msk), oz = __shfl_xor(z, msk);
        float nm = fmaxf(m, om);
        z = z * __expf(m - nm) + oz * __expf(om - nm);
        m = nm;
    }
    // recompute target logit from the LDS A-tile (no cross-block logits dependency)
    int t = targets[row];
    float dot = 0.f;
    for (int k = q*64; k < q*64 + 64; ++k)
        dot += bf2f(As[rr*256 + (k ^ ((rr & 7) << 3))]) * bf2f(WlmT[(size_t)t*EE + k]);
    dot += __shfl_xor(dot, 1);
    dot += __shfl_xor(dot, 2);
    if (q == 0) {
        float loss_i = (m + logf(z)) - (dot + blm[t]);
        atomicAdd(loss_cell, loss_i * (1.0f / NROWS));
    }
}

extern "C" void kernel_launch(void* const* d_in, const int* in_sizes, int n_in,
                              void* d_out, int out_size, void* d_ws, size_t ws_size,
                              hipStream_t stream) {
    const int*   idxs    = (const int*)d_in[0];
    const int*   targets = (const int*)d_in[1];
    const float* emb     = (const float*)d_in[2];
    const float* pos     = (const float*)d_in[3];
    const float* Wq      = (const float*)d_in[4];
    const float* Wk      = (const float*)d_in[5];
    const float* Wv      = (const float*)d_in[6];
    const float* Wfc     = (const float*)d_in[7];
    const float* bfc     = (const float*)d_in[8];
    const float* Wlm     = (const float*)d_in[9];
    const float* blm     = (const float*)d_in[10];
    float* out = (float*)d_out;
    float* loss_cell = out + (size_t)NROWS * VV;

    float* ws = (float*)d_ws;
    float*  xa       = ws;                       // [1024,256]
    float*  xb       = xa + NROWS*EE;
    float*  qt       = xb + NROWS*EE;            // [B,H,T]
    float*  kt       = qt + NROWS*EE;
    float*  vt       = kt + NROWS*EE;
    float*  pm       = vt + NROWS*EE;            // [1024,128]
    float*  pz       = pm + NROWS*128;
    int*    row_done = (int*)(pz + NROWS*128);   // 16 counters (+pad to 64)
    ushort* WTs      = (ushort*)(row_done + 64); // 20 * 256*256 bf16
    ushort* WlmT     = WTs + 20*EE*EE;           // 8192*256 bf16

    prep_kernel<<<1089, 256, 0, stream>>>(idxs, emb, pos, Wq, Wk, Wv, Wfc, Wlm,
                                          xa, WTs, WlmT, loss_cell, row_done);

    for (int l = 0; l < LL; ++l) {
        float* xi = (l & 1) ? xb : xa;
        float* xo = (l & 1) ? xa : xb;
        qkv_mfma<<<dim3(12, 16), 256, 0, stream>>>(xi, WTs + (size_t)l*4*EE*EE, qt, kt, vt);
        attn_kernel<<<256, 256, 0, stream>>>(qt, kt, vt, xi);
        fc_mfma<<<dim3(4, 16), 256, 0, stream>>>(xi, WTs + (size_t)(l*4 + 3)*EE*EE,
                                                 bfc + l*EE, xo);
    }

    lm_loss_kernel<<<dim3(VV/64, NROWS/64), 256, 0, stream>>>(
        xb, WlmT, blm, targets, out, pm, pz, row_done, loss_cell);
}

// Round 8
// 264.362 us; speedup vs baseline: 4.1582x; 1.2008x over previous
//
#include <hip/hip_runtime.h>

#define BB 8
#define TT 128
#define EE 256
#define VV 8192
#define LL 5
#define NROWS (BB*TT)   // 1024

typedef __attribute__((ext_vector_type(8))) short bf16x8;
typedef __attribute__((ext_vector_type(4))) float f32x4;

__device__ inline ushort f2bf(float f) {
    union { float f; unsigned u; } c; c.f = f;
    unsigned u = c.u;
    return (ushort)((u + 0x7FFF + ((u >> 16) & 1)) >> 16);  // RNE
}

// ---------------- prep: loss-cell zero + WlmT + per-layer weight transposes + embedding ----
__global__ __launch_bounds__(256) void prep_kernel(
        const int* __restrict__ idxs, const float* __restrict__ emb, const float* __restrict__ pos,
        const float* __restrict__ Wq, const float* __restrict__ Wk,
        const float* __restrict__ Wv, const float* __restrict__ Wfc,
        const float* __restrict__ Wlm,
        float* __restrict__ x0, ushort* __restrict__ WTs, ushort* __restrict__ WlmT,
        float* __restrict__ loss_cell) {
    int id = blockIdx.x;
    if (id == 0) {
        if (threadIdx.x == 0) *loss_cell = 0.f;
        return;
    }
    if (id < 513) {
        __shared__ ushort ts[64][72];
        int idw = id - 1;
        int v0 = (idw & 127) * 64, k0 = (idw >> 7) * 64;
        int lane = threadIdx.x & 63, w = threadIdx.x >> 6;
        for (int kk = w; kk < 64; kk += 4)
            ts[lane][kk] = f2bf(Wlm[(size_t)(k0 + kk)*VV + v0 + lane]);
        __syncthreads();
        for (int vv = w; vv < 64; vv += 4)
            WlmT[(size_t)(v0 + vv)*EE + k0 + lane] = ts[vv][lane];
        return;
    }
    if (id < 833) {
        __shared__ ushort ts[64][72];
        int idm = id - 513;
        int mat = idm >> 4, tile = idm & 15;
        int l = mat >> 2, type = mat & 3;
        const float* src = (type == 0 ? Wq : type == 1 ? Wk : type == 2 ? Wv : Wfc) + l*EE*EE;
        ushort* dst = WTs + mat*EE*EE;
        int i0 = (tile >> 2) * 64, o0 = (tile & 3) * 64;
        int lane = threadIdx.x & 63, w = threadIdx.x >> 6;
        for (int ii = w; ii < 64; ii += 4)
            ts[lane][ii] = f2bf(src[(i0 + ii)*EE + o0 + lane]);
        __syncthreads();
        for (int oo = w; oo < 64; oo += 4)
            dst[(o0 + oo)*EE + i0 + lane] = ts[oo][lane];
        return;
    }
    int h = threadIdx.x;
    int row0 = (id - 833) * 4;
    for (int r = 0; r < 4; ++r) {
        int row = row0 + r;
        x0[row*EE + h] = emb[(size_t)idxs[row]*EE + h] + pos[(row & (TT-1))*EE + h];
    }
}

// ---------------- q,k,v = x @ W (3 GEMMs along grid.x), transposed f32 stores [B,H,T]
__global__ __launch_bounds__(256) void qkv_mfma(
        const float* __restrict__ xin, const ushort* __restrict__ WTl,
        float* __restrict__ qt, float* __restrict__ kt, float* __restrict__ vt) {
    __shared__ __align__(16) ushort As[64*256];
    __shared__ __align__(16) ushort Bs[64*256];
    int tid = threadIdx.x, lane = tid & 63, w = tid >> 6;
    int mat = blockIdx.x >> 2;
    int c0 = (blockIdx.x & 3) * 64;
    int r0 = blockIdx.y * 64;
    const ushort* WT = WTl + (size_t)mat*EE*EE;
    float* o = mat == 0 ? qt : (mat == 1 ? kt : vt);

    for (int rr = w; rr < 64; rr += 4) {
        float4 v = *(const float4*)&xin[(size_t)(r0 + rr)*EE + lane*4];
        ushort4 hh; hh.x = f2bf(v.x); hh.y = f2bf(v.y); hh.z = f2bf(v.z); hh.w = f2bf(v.w);
        *(ushort4*)&As[rr*256 + ((lane*4) ^ ((rr & 7) << 3))] = hh;
    }
    for (int it = 0; it < 8; ++it) {
        int c = w*16 + (lane >> 5) + 2*it;
        int k0i = (lane & 31) * 8;
        uint4 v = *(const uint4*)&WT[(size_t)(c0 + c)*EE + k0i];
        *(uint4*)&Bs[c*256 + (k0i ^ ((c & 7) << 3))] = v;
    }
    __syncthreads();
    f32x4 acc[4] = {};
    int rband = w*16 + (lane & 15);
    int kq = (lane >> 4) * 8;
    for (int ks = 0; ks < 8; ++ks) {
        int kk = ks*32 + kq;
        bf16x8 a = *(const bf16x8*)&As[rband*256 + (kk ^ ((rband & 7) << 3))];
        #pragma unroll
        for (int n = 0; n < 4; ++n) {
            int c = n*16 + (lane & 15);
            bf16x8 b = *(const bf16x8*)&Bs[c*256 + (kk ^ ((c & 7) << 3))];
            acc[n] = __builtin_amdgcn_mfma_f32_16x16x32_bf16(a, b, acc[n], 0, 0, 0);
        }
    }
    int grow0 = r0 + w*16 + ((lane >> 4) << 2);
    int b = grow0 >> 7, t0 = grow0 & (TT-1);
    #pragma unroll
    for (int n = 0; n < 4; ++n) {
        int h = c0 + n*16 + (lane & 15);
        float4 vv = make_float4(acc[n][0], acc[n][1], acc[n][2], acc[n][3]);
        *(float4*)&o[((size_t)(b*EE + h))*TT + t0] = vv;
    }
}

// ---------------- attention v1 (R4-verified): 2 heads per 256-thr block, grid 1024
__global__ __launch_bounds__(256) void attn_kernel(
        const float* __restrict__ qt, const float* __restrict__ kt,
        const float* __restrict__ vt, float* __restrict__ x) {
    int pair = threadIdx.x >> 7;
    int t = threadIdx.x & (TT-1);
    int bh = blockIdx.x*2 + pair;
    int b = bh >> 8, h = bh & 255;
    __shared__ float qs[2][TT], ks[2][TT], vs[2][TT], ms[2][TT], rzs[2][TT];
    int base = bh * TT;
    qs[pair][t] = qt[base + t];
    ks[pair][t] = kt[base + t];
    vs[pair][t] = vt[base + t];
    __syncthreads();
    float k = ks[pair][t];
    float m = -INFINITY;
    for (int i = t; i < TT; ++i) m = fmaxf(m, qs[pair][i] * k);
    float z = 0.f;
    for (int i = t; i < TT; ++i) z += __expf(qs[pair][i] * k - m);
    ms[pair][t] = m; rzs[pair][t] = 1.f / z;
    __syncthreads();
    float q = qs[pair][t];
    float acc = 0.f;
    for (int j = 0; j <= t; ++j)
        acc += __expf(q * ks[pair][j] - ms[pair][j]) * rzs[pair][j] * vs[pair][j];
    x[(size_t)(b*TT + t)*EE + h] += acc;
}

// ---------------- xout = xin + relu(xin @ Wfc + bfc)
__global__ __launch_bounds__(256) void fc_mfma(
        const float* __restrict__ xin, const ushort* __restrict__ WT,
        const float* __restrict__ bfc, float* __restrict__ xout) {
    __shared__ __align__(16) ushort As[64*256];
    __shared__ __align__(16) ushort Bs[64*256];
    int tid = threadIdx.x, lane = tid & 63, w = tid >> 6;
    int c0 = blockIdx.x * 64;
    int r0 = blockIdx.y * 64;

    for (int rr = w; rr < 64; rr += 4) {
        float4 v = *(const float4*)&xin[(size_t)(r0 + rr)*EE + lane*4];
        ushort4 hh; hh.x = f2bf(v.x); hh.y = f2bf(v.y); hh.z = f2bf(v.z); hh.w = f2bf(v.w);
        *(ushort4*)&As[rr*256 + ((lane*4) ^ ((rr & 7) << 3))] = hh;
    }
    for (int it = 0; it < 8; ++it) {
        int c = w*16 + (lane >> 5) + 2*it;
        int k0i = (lane & 31) * 8;
        uint4 v = *(const uint4*)&WT[(size_t)(c0 + c)*EE + k0i];
        *(uint4*)&Bs[c*256 + (k0i ^ ((c & 7) << 3))] = v;
    }
    __syncthreads();
    f32x4 acc[4] = {};
    int rband = w*16 + (lane & 15);
    int kq = (lane >> 4) * 8;
    for (int ks = 0; ks < 8; ++ks) {
        int kk = ks*32 + kq;
        bf16x8 a = *(const bf16x8*)&As[rband*256 + (kk ^ ((rband & 7) << 3))];
        #pragma unroll
        for (int n = 0; n < 4; ++n) {
            int c = n*16 + (lane & 15);
            bf16x8 b = *(const bf16x8*)&Bs[c*256 + (kk ^ ((c & 7) << 3))];
            acc[n] = __builtin_amdgcn_mfma_f32_16x16x32_bf16(a, b, acc[n], 0, 0, 0);
        }
    }
    int grow0 = r0 + w*16 + ((lane >> 4) << 2);
    #pragma unroll
    for (int n = 0; n < 4; ++n) {
        int col = c0 + n*16 + (lane & 15);
        float bias = bfc[col];
        #pragma unroll
        for (int j = 0; j < 4; ++j) {
            size_t idx = (size_t)(grow0 + j)*EE + col;
            xout[idx] = xin[idx] + fmaxf(acc[n][j] + bias, 0.f);
        }
    }
}

// ---------------- lm v2: A in LDS (32KB), B streamed from L2 (reg dbuf), float4 stores
__global__ __launch_bounds__(256) void lm_mfma_kernel(
        const float* __restrict__ x, const ushort* __restrict__ WlmT,
        const float* __restrict__ blm, float* __restrict__ out,
        float* __restrict__ pm, float* __restrict__ pz) {
    __shared__ __align__(16) ushort As[64*256];   // 32KB; reused as f32[64][68] store staging
    int tid = threadIdx.x;
    int lane = tid & 63, w = tid >> 6;
    int c0 = blockIdx.x * 64;
    int r0 = blockIdx.y * 64;

    // stage A: wave reads one full row (64 lanes x float4) per iter
    for (int rr = w; rr < 64; rr += 4) {
        float4 v = *(const float4*)&x[(size_t)(r0 + rr)*EE + lane*4];
        ushort4 hh; hh.x = f2bf(v.x); hh.y = f2bf(v.y); hh.z = f2bf(v.z); hh.w = f2bf(v.w);
        *(ushort4*)&As[rr*256 + ((lane*4) ^ ((rr & 7) << 3))] = hh;
    }
    __syncthreads();

    int rband = w*16 + (lane & 15);
    int kq = (lane >> 4) * 8;
    // B fragment base: col = c0 + n*16 + (lane&15), k offset = ks*32 + kq
    const ushort* bp = WlmT + (size_t)(c0 + (lane & 15))*EE + kq;

    f32x4 acc[4] = {};
    bf16x8 bc0 = *(const bf16x8*)&bp[0*16*EE];
    bf16x8 bc1 = *(const bf16x8*)&bp[1*16*EE];
    bf16x8 bc2 = *(const bf16x8*)&bp[2*16*EE];
    bf16x8 bc3 = *(const bf16x8*)&bp[3*16*EE];
    #pragma unroll
    for (int ks = 0; ks < 8; ++ks) {
        bf16x8 bn0, bn1, bn2, bn3;
        if (ks < 7) {
            int ko = (ks + 1)*32;
            bn0 = *(const bf16x8*)&bp[ko + 0*16*EE];
            bn1 = *(const bf16x8*)&bp[ko + 1*16*EE];
            bn2 = *(const bf16x8*)&bp[ko + 2*16*EE];
            bn3 = *(const bf16x8*)&bp[ko + 3*16*EE];
        }
        int kk = ks*32 + kq;
        bf16x8 a = *(const bf16x8*)&As[rband*256 + (kk ^ ((rband & 7) << 3))];
        acc[0] = __builtin_amdgcn_mfma_f32_16x16x32_bf16(a, bc0, acc[0], 0, 0, 0);
        acc[1] = __builtin_amdgcn_mfma_f32_16x16x32_bf16(a, bc1, acc[1], 0, 0, 0);
        acc[2] = __builtin_amdgcn_mfma_f32_16x16x32_bf16(a, bc2, acc[2], 0, 0, 0);
        acc[3] = __builtin_amdgcn_mfma_f32_16x16x32_bf16(a, bc3, acc[3], 0, 0, 0);
        if (ks < 7) { bc0 = bn0; bc1 = bn1; bc2 = bn2; bc3 = bn3; }
    }
    __syncthreads();   // done reading As; reuse as f32 staging

    float* fst = (float*)As;               // [64][68] padded
    float bias[4];
    #pragma unroll
    for (int n = 0; n < 4; ++n) bias[n] = blm[c0 + n*16 + (lane & 15)];
    int rw = w*16 + (lane >> 4)*4;         // tile-row base for j=0
    int rowg = r0 + rw;
    #pragma unroll
    for (int j = 0; j < 4; ++j) {
        float vals[4];
        float vmax = -INFINITY;
        #pragma unroll
        for (int n = 0; n < 4; ++n) {
            vals[n] = acc[n][j] + bias[n];
            fst[(rw + j)*68 + n*16 + (lane & 15)] = vals[n];
            vmax = fmaxf(vmax, vals[n]);
        }
        #pragma unroll
        for (int m = 1; m <= 8; m <<= 1) vmax = fmaxf(vmax, __shfl_xor(vmax, m));
        float z = 0.f;
        #pragma unroll
        for (int n = 0; n < 4; ++n) z += __expf(vals[n] - vmax);
        #pragma unroll
        for (int m = 1; m <= 8; m <<= 1) z += __shfl_xor(z, m);
        if ((lane & 15) == 0) {
            pm[(size_t)(rowg + j)*128 + blockIdx.x] = vmax;
            pz[(size_t)(rowg + j)*128 + blockIdx.x] = z;
        }
    }
    __syncthreads();
    // coalesced store: 16 threads cover one row (64 cols) as 4x float4 each thread
    #pragma unroll
    for (int it = 0; it < 4; ++it) {
        int k = tid + it*256;
        int row = k >> 4, c4 = (k & 15)*4;
        float4 v = *(float4*)&fst[row*68 + c4];
        *(float4*)&out[(size_t)(r0 + row)*VV + c0 + c4] = v;
    }
}

// ---------------- per-row loss from partials, atomicAdd mean into pre-zeroed loss cell
__global__ void loss_kernel(const float* __restrict__ pm, const float* __restrict__ pz,
                            const float* __restrict__ logits, const int* __restrict__ targets,
                            float* __restrict__ out_last) {
    int r = blockIdx.x;
    int t = threadIdx.x;             // 128
    __shared__ float sm[128], sz[128];
    float m = pm[(size_t)r*128 + t];
    float z = pz[(size_t)r*128 + t];
    sm[t] = m; __syncthreads();
    for (int s = 64; s > 0; s >>= 1) {
        if (t < s) sm[t] = fmaxf(sm[t], sm[t + s]);
        __syncthreads();
    }
    float M = sm[0];
    sz[t] = z * __expf(m - M); __syncthreads();
    for (int s = 64; s > 0; s >>= 1) {
        if (t < s) sz[t] += sz[t + s];
        __syncthreads();
    }
    if (t == 0) {
        float lse = M + logf(sz[0]);
        atomicAdd(out_last, (lse - logits[(size_t)r*VV + targets[r]]) * (1.0f / NROWS));
    }
}

extern "C" void kernel_launch(void* const* d_in, const int* in_sizes, int n_in,
                              void* d_out, int out_size, void* d_ws, size_t ws_size,
                              hipStream_t stream) {
    const int*   idxs    = (const int*)d_in[0];
    const int*   targets = (const int*)d_in[1];
    const float* emb     = (const float*)d_in[2];
    const float* pos     = (const float*)d_in[3];
    const float* Wq      = (const float*)d_in[4];
    const float* Wk      = (const float*)d_in[5];
    const float* Wv      = (const float*)d_in[6];
    const float* Wfc     = (const float*)d_in[7];
    const float* bfc     = (const float*)d_in[8];
    const float* Wlm     = (const float*)d_in[9];
    const float* blm     = (const float*)d_in[10];
    float* out = (float*)d_out;
    float* loss_cell = out + (size_t)NROWS * VV;

    float* ws = (float*)d_ws;
    float*  xa   = ws;                       // [1024,256]
    float*  xb   = xa + NROWS*EE;
    float*  qt   = xb + NROWS*EE;            // [B,H,T]
    float*  kt   = qt + NROWS*EE;
    float*  vt   = kt + NROWS*EE;
    float*  pm   = vt + NROWS*EE;            // [1024,128]
    float*  pz   = pm + NROWS*128;
    ushort* WTs  = (ushort*)(pz + NROWS*128);   // 20 * 256*256 bf16
    ushort* WlmT = WTs + 20*EE*EE;              // 8192*256 bf16

    prep_kernel<<<1089, 256, 0, stream>>>(idxs, emb, pos, Wq, Wk, Wv, Wfc, Wlm,
                                          xa, WTs, WlmT, loss_cell);

    for (int l = 0; l < LL; ++l) {
        float* xi = (l & 1) ? xb : xa;
        float* xo = (l & 1) ? xa : xb;
        qkv_mfma<<<dim3(12, 16), 256, 0, stream>>>(xi, WTs + (size_t)l*4*EE*EE, qt, kt, vt);
        attn_kernel<<<1024, 256, 0, stream>>>(qt, kt, vt, xi);
        fc_mfma<<<dim3(4, 16), 256, 0, stream>>>(xi, WTs + (size_t)(l*4 + 3)*EE*EE,
                                                 bfc + l*EE, xo);
    }

    lm_mfma_kernel<<<dim3(VV/64, NROWS/64), 256, 0, stream>>>(xb, WlmT, blm, out, pm, pz);
    loss_kernel<<<NROWS, 128, 0, stream>>>(pm, pz, out, targets, loss_cell);
}

// Round 9
// 241.808 us; speedup vs baseline: 4.5460x; 1.0933x over previous
//
#include <hip/hip_runtime.h>

#define BB 8
#define TT 128
#define EE 256
#define VV 8192
#define LL 5
#define NROWS (BB*TT)   // 1024

typedef __attribute__((ext_vector_type(8))) short bf16x8;
typedef __attribute__((ext_vector_type(4))) float f32x4;

__device__ inline ushort f2bf(float f) {
    union { float f; unsigned u; } c; c.f = f;
    unsigned u = c.u;
    return (ushort)((u + 0x7FFF + ((u >> 16) & 1)) >> 16);  // RNE
}

// ---------------- prep: loss-cell zero + WlmT + per-layer weight transposes + embedding ----
__global__ __launch_bounds__(256) void prep_kernel(
        const int* __restrict__ idxs, const float* __restrict__ emb, const float* __restrict__ pos,
        const float* __restrict__ Wq, const float* __restrict__ Wk,
        const float* __restrict__ Wv, const float* __restrict__ Wfc,
        const float* __restrict__ Wlm,
        float* __restrict__ x0, ushort* __restrict__ WTs, ushort* __restrict__ WlmT,
        float* __restrict__ loss_cell) {
    int id = blockIdx.x;
    if (id == 0) {
        if (threadIdx.x == 0) *loss_cell = 0.f;
        return;
    }
    if (id < 513) {
        __shared__ ushort ts[64][72];
        int idw = id - 1;
        int v0 = (idw & 127) * 64, k0 = (idw >> 7) * 64;
        int lane = threadIdx.x & 63, w = threadIdx.x >> 6;
        for (int kk = w; kk < 64; kk += 4)
            ts[lane][kk] = f2bf(Wlm[(size_t)(k0 + kk)*VV + v0 + lane]);
        __syncthreads();
        for (int vv = w; vv < 64; vv += 4)
            WlmT[(size_t)(v0 + vv)*EE + k0 + lane] = ts[vv][lane];
        return;
    }
    if (id < 833) {
        __shared__ ushort ts[64][72];
        int idm = id - 513;
        int mat = idm >> 4, tile = idm & 15;
        int l = mat >> 2, type = mat & 3;
        const float* src = (type == 0 ? Wq : type == 1 ? Wk : type == 2 ? Wv : Wfc) + l*EE*EE;
        ushort* dst = WTs + mat*EE*EE;
        int i0 = (tile >> 2) * 64, o0 = (tile & 3) * 64;
        int lane = threadIdx.x & 63, w = threadIdx.x >> 6;
        for (int ii = w; ii < 64; ii += 4)
            ts[lane][ii] = f2bf(src[(i0 + ii)*EE + o0 + lane]);
        __syncthreads();
        for (int oo = w; oo < 64; oo += 4)
            dst[(o0 + oo)*EE + i0 + lane] = ts[oo][lane];
        return;
    }
    int h = threadIdx.x;
    int row0 = (id - 833) * 4;
    for (int r = 0; r < 4; ++r) {
        int row = row0 + r;
        x0[row*EE + h] = emb[(size_t)idxs[row]*EE + h] + pos[(row & (TT-1))*EE + h];
    }
}

// ---------------- fused qkv+attn: block = (batch b, 8 heads). grid 256 x 512 threads.
// Stages x_b in LDS, computes q|k|v cols via MFMA, attention fully in LDS, RMWs 8 x-cols.
__global__ __launch_bounds__(512) void qkv_attn_kernel(
        float* __restrict__ x, const ushort* __restrict__ WTl) {
    __shared__ __align__(16) ushort Xs[128*256];   // 64KB swizzled bf16 x_b
    __shared__ __align__(16) ushort Bs[32*256];    // 16KB swizzled bf16 [q8|k8|v8|pad8]
    __shared__ float QS[8*132], KS[8*132], VS[8*132], MS[8*132], RV[8*132];
    int tid = threadIdx.x, lane = tid & 63, w = tid >> 6;   // 8 waves
    int b  = blockIdx.x >> 5;
    int h0 = (blockIdx.x & 31) * 8;

    // stage x_b: one row (256 f32) per wave-iter
    for (int rr = w; rr < 128; rr += 8) {
        float4 v = *(const float4*)&x[(size_t)(b*TT + rr)*EE + lane*4];
        ushort4 hh; hh.x = f2bf(v.x); hh.y = f2bf(v.y); hh.z = f2bf(v.z); hh.w = f2bf(v.w);
        *(ushort4*)&Xs[rr*256 + ((lane*4) ^ ((rr & 7) << 3))] = hh;
    }
    // stage B: 32 cols (q8|k8|v8|zero8) x K=256
    {
        int c = tid >> 4;               // 0..31
        int kb = (tid & 15) * 16;       // 0..240
        uint4 v0 = make_uint4(0,0,0,0), v1 = v0;
        if (c < 24) {
            int mat = c >> 3;           // 0=q,1=k,2=v
            int col = h0 + (c & 7);
            const ushort* src = WTl + (size_t)mat*EE*EE + (size_t)col*EE + kb;
            v0 = *(const uint4*)&src[0];
            v1 = *(const uint4*)&src[8];
        }
        *(uint4*)&Bs[c*256 + (kb ^ ((c & 7) << 3))] = v0;
        *(uint4*)&Bs[c*256 + ((kb + 8) ^ ((c & 7) << 3))] = v1;
    }
    __syncthreads();

    // qkv MFMA: wave w -> rows w*16..w*16+15, 2 col-tiles (32 cols, 24 valid)
    {
        f32x4 acc[2] = {};
        int rband = w*16 + (lane & 15);
        int kq = (lane >> 4) * 8;
        for (int ks = 0; ks < 8; ++ks) {
            int kk = ks*32 + kq;
            bf16x8 a = *(const bf16x8*)&Xs[rband*256 + (kk ^ ((rband & 7) << 3))];
            #pragma unroll
            for (int ct = 0; ct < 2; ++ct) {
                int c = ct*16 + (lane & 15);
                bf16x8 bb = *(const bf16x8*)&Bs[c*256 + (kk ^ ((c & 7) << 3))];
                acc[ct] = __builtin_amdgcn_mfma_f32_16x16x32_bf16(a, bb, acc[ct], 0, 0, 0);
            }
        }
        int r_ = w*16 + ((lane >> 4) << 2);
        #pragma unroll
        for (int ct = 0; ct < 2; ++ct) {
            int col24 = ct*16 + (lane & 15);
            #pragma unroll
            for (int j = 0; j < 4; ++j) {
                float val = acc[ct][j];
                int row = r_ + j;
                if (col24 < 8)       QS[col24*132 + row] = val;
                else if (col24 < 16) KS[(col24-8)*132 + row] = val;
                else if (col24 < 24) VS[(col24-16)*132 + row] = val;
            }
        }
    }
    __syncthreads();

    // attention: head g = wave w, 64 lanes; 2 cols/rows per lane
    int g = w, lg = lane;
    // phase 1: per-column stats over i >= j
    {
        int j0 = lg*2;
        float k0 = KS[g*132 + j0], k1 = KS[g*132 + j0 + 1];
        float m0 = -INFINITY, m1 = -INFINITY;
        for (int i = j0; i < TT; ++i) {
            float qi = QS[g*132 + i];
            m0 = fmaxf(m0, qi*k0);
            m1 = (i >= j0+1) ? fmaxf(m1, qi*k1) : m1;
        }
        float z0 = 0.f, z1 = 0.f;
        for (int i = j0; i < TT; ++i) {
            float qi = QS[g*132 + i];
            z0 += __expf(qi*k0 - m0);
            z1 += (i >= j0+1) ? __expf(qi*k1 - m1) : 0.f;
        }
        MS[g*132 + j0]     = m0;
        MS[g*132 + j0 + 1] = m1;
        RV[g*132 + j0]     = VS[g*132 + j0] / z0;
        RV[g*132 + j0 + 1] = VS[g*132 + j0 + 1] / z1;
    }
    __syncthreads();
    // phase 2: per-row out_i = sum_{j<=i} exp(q_i k_j - m_j) * rv_j
    float a0 = 0.f, a1 = 0.f;
    {
        int i0 = lg*2;
        float q0 = QS[g*132 + i0], q1 = QS[g*132 + i0 + 1];
        for (int j = 0; j <= i0 + 1; ++j) {
            float kj = KS[g*132 + j], mj = MS[g*132 + j], rj = RV[g*132 + j];
            float e0 = __expf(q0*kj - mj) * rj;
            float e1 = __expf(q1*kj - mj) * rj;
            a0 += (j <= i0) ? e0 : 0.f;
            a1 += e1;
        }
    }
    __syncthreads();              // all phase-1/2 reads of VS done
    VS[g*132 + lg*2]     = a0;
    VS[g*132 + lg*2 + 1] = a1;
    __syncthreads();

    // coalesced RMW of x: 4 threads per row, float2 per thread (8 cols)
    {
        int row = tid >> 2, cp = (tid & 3) * 2;
        size_t gx = (size_t)(b*TT + row)*EE + h0 + cp;
        float2 xv = *(float2*)&x[gx];
        xv.x += VS[cp*132 + row];
        xv.y += VS[(cp+1)*132 + row];
        *(float2*)&x[gx] = xv;
    }
}

// ---------------- xout = xin + relu(xin @ Wfc + bfc)
__global__ __launch_bounds__(256) void fc_mfma(
        const float* __restrict__ xin, const ushort* __restrict__ WT,
        const float* __restrict__ bfc, float* __restrict__ xout) {
    __shared__ __align__(16) ushort As[64*256];
    __shared__ __align__(16) ushort Bs[64*256];
    int tid = threadIdx.x, lane = tid & 63, w = tid >> 6;
    int c0 = blockIdx.x * 64;
    int r0 = blockIdx.y * 64;

    for (int rr = w; rr < 64; rr += 4) {
        float4 v = *(const float4*)&xin[(size_t)(r0 + rr)*EE + lane*4];
        ushort4 hh; hh.x = f2bf(v.x); hh.y = f2bf(v.y); hh.z = f2bf(v.z); hh.w = f2bf(v.w);
        *(ushort4*)&As[rr*256 + ((lane*4) ^ ((rr & 7) << 3))] = hh;
    }
    for (int it = 0; it < 8; ++it) {
        int c = w*16 + (lane >> 5) + 2*it;
        int k0i = (lane & 31) * 8;
        uint4 v = *(const uint4*)&WT[(size_t)(c0 + c)*EE + k0i];
        *(uint4*)&Bs[c*256 + (k0i ^ ((c & 7) << 3))] = v;
    }
    __syncthreads();
    f32x4 acc[4] = {};
    int rband = w*16 + (lane & 15);
    int kq = (lane >> 4) * 8;
    for (int ks = 0; ks < 8; ++ks) {
        int kk = ks*32 + kq;
        bf16x8 a = *(const bf16x8*)&As[rband*256 + (kk ^ ((rband & 7) << 3))];
        #pragma unroll
        for (int n = 0; n < 4; ++n) {
            int c = n*16 + (lane & 15);
            bf16x8 b = *(const bf16x8*)&Bs[c*256 + (kk ^ ((c & 7) << 3))];
            acc[n] = __builtin_amdgcn_mfma_f32_16x16x32_bf16(a, b, acc[n], 0, 0, 0);
        }
    }
    int grow0 = r0 + w*16 + ((lane >> 4) << 2);
    #pragma unroll
    for (int n = 0; n < 4; ++n) {
        int col = c0 + n*16 + (lane & 15);
        float bias = bfc[col];
        #pragma unroll
        for (int j = 0; j < 4; ++j) {
            size_t idx = (size_t)(grow0 + j)*EE + col;
            xout[idx] = xin[idx] + fmaxf(acc[n][j] + bias, 0.f);
        }
    }
}

// ---------------- lm v3: A+B in LDS (R4-verified core) + coalesced f4 store epilogue
__global__ __launch_bounds__(256) void lm_mfma_kernel(
        const float* __restrict__ x, const ushort* __restrict__ WlmT,
        const float* __restrict__ blm, float* __restrict__ out,
        float* __restrict__ pm, float* __restrict__ pz) {
    __shared__ __align__(16) ushort As[64*256];   // reused as f32 [64][68] store staging
    __shared__ __align__(16) ushort Bs[64*256];
    int tid = threadIdx.x;
    int lane = tid & 63, w = tid >> 6;
    int c0 = blockIdx.x * 64;
    int r0 = blockIdx.y * 64;

    for (int rr = w; rr < 64; rr += 4) {
        float4 v = *(const float4*)&x[(size_t)(r0 + rr)*EE + lane*4];
        ushort4 hh; hh.x = f2bf(v.x); hh.y = f2bf(v.y); hh.z = f2bf(v.z); hh.w = f2bf(v.w);
        *(ushort4*)&As[rr*256 + ((lane*4) ^ ((rr & 7) << 3))] = hh;
    }
    for (int it = 0; it < 8; ++it) {
        int c = w*16 + (lane >> 5) + 2*it;
        int k0i = (lane & 31) * 8;
        uint4 v = *(const uint4*)&WlmT[(size_t)(c0 + c)*EE + k0i];
        *(uint4*)&Bs[c*256 + (k0i ^ ((c & 7) << 3))] = v;
    }
    __syncthreads();

    f32x4 acc[4] = {};
    int rband = w*16 + (lane & 15);
    int kq = (lane >> 4) * 8;
    for (int ks = 0; ks < 8; ++ks) {
        int kk = ks*32 + kq;
        bf16x8 a = *(const bf16x8*)&As[rband*256 + (kk ^ ((rband & 7) << 3))];
        #pragma unroll
        for (int n = 0; n < 4; ++n) {
            int c = n*16 + (lane & 15);
            bf16x8 b = *(const bf16x8*)&Bs[c*256 + (kk ^ ((c & 7) << 3))];
            acc[n] = __builtin_amdgcn_mfma_f32_16x16x32_bf16(a, b, acc[n], 0, 0, 0);
        }
    }
    __syncthreads();   // done with As; reuse as f32 staging

    float* fst = (float*)As;               // [64][68] padded
    float bias[4];
    #pragma unroll
    for (int n = 0; n < 4; ++n) bias[n] = blm[c0 + n*16 + (lane & 15)];
    int rw = w*16 + (lane >> 4)*4;
    int rowg = r0 + rw;
    #pragma unroll
    for (int j = 0; j < 4; ++j) {
        float vals[4];
        float vmax = -INFINITY;
        #pragma unroll
        for (int n = 0; n < 4; ++n) {
            vals[n] = acc[n][j] + bias[n];
            fst[(rw + j)*68 + n*16 + (lane & 15)] = vals[n];
            vmax = fmaxf(vmax, vals[n]);
        }
        #pragma unroll
        for (int m = 1; m <= 8; m <<= 1) vmax = fmaxf(vmax, __shfl_xor(vmax, m));
        float z = 0.f;
        #pragma unroll
        for (int n = 0; n < 4; ++n) z += __expf(vals[n] - vmax);
        #pragma unroll
        for (int m = 1; m <= 8; m <<= 1) z += __shfl_xor(z, m);
        if ((lane & 15) == 0) {
            pm[(size_t)(rowg + j)*128 + blockIdx.x] = vmax;
            pz[(size_t)(rowg + j)*128 + blockIdx.x] = z;
        }
    }
    __syncthreads();
    #pragma unroll
    for (int it = 0; it < 4; ++it) {
        int k = tid + it*256;
        int row = k >> 4, c4 = (k & 15)*4;
        float4 v = *(float4*)&fst[row*68 + c4];
        *(float4*)&out[(size_t)(r0 + row)*VV + c0 + c4] = v;
    }
}

// ---------------- per-row loss from partials, atomicAdd mean into pre-zeroed loss cell
__global__ void loss_kernel(const float* __restrict__ pm, const float* __restrict__ pz,
                            const float* __restrict__ logits, const int* __restrict__ targets,
                            float* __restrict__ out_last) {
    int r = blockIdx.x;
    int t = threadIdx.x;             // 128
    __shared__ float sm[128], sz[128];
    float m = pm[(size_t)r*128 + t];
    float z = pz[(size_t)r*128 + t];
    sm[t] = m; __syncthreads();
    for (int s = 64; s > 0; s >>= 1) {
        if (t < s) sm[t] = fmaxf(sm[t], sm[t + s]);
        __syncthreads();
    }
    float M = sm[0];
    sz[t] = z * __expf(m - M); __syncthreads();
    for (int s = 64; s > 0; s >>= 1) {
        if (t < s) sz[t] += sz[t + s];
        __syncthreads();
    }
    if (t == 0) {
        float lse = M + logf(sz[0]);
        atomicAdd(out_last, (lse - logits[(size_t)r*VV + targets[r]]) * (1.0f / NROWS));
    }
}

extern "C" void kernel_launch(void* const* d_in, const int* in_sizes, int n_in,
                              void* d_out, int out_size, void* d_ws, size_t ws_size,
                              hipStream_t stream) {
    const int*   idxs    = (const int*)d_in[0];
    const int*   targets = (const int*)d_in[1];
    const float* emb     = (const float*)d_in[2];
    const float* pos     = (const float*)d_in[3];
    const float* Wq      = (const float*)d_in[4];
    const float* Wk      = (const float*)d_in[5];
    const float* Wv      = (const float*)d_in[6];
    const float* Wfc     = (const float*)d_in[7];
    const float* bfc     = (const float*)d_in[8];
    const float* Wlm     = (const float*)d_in[9];
    const float* blm     = (const float*)d_in[10];
    float* out = (float*)d_out;
    float* loss_cell = out + (size_t)NROWS * VV;

    float* ws = (float*)d_ws;
    float*  xa   = ws;                          // [1024,256]
    float*  xb   = xa + NROWS*EE;
    float*  pm   = xb + NROWS*EE;               // [1024,128]
    float*  pz   = pm + NROWS*128;
    ushort* WTs  = (ushort*)(pz + NROWS*128);   // 20 * 256*256 bf16
    ushort* WlmT = WTs + 20*EE*EE;              // 8192*256 bf16

    prep_kernel<<<1089, 256, 0, stream>>>(idxs, emb, pos, Wq, Wk, Wv, Wfc, Wlm,
                                          xa, WTs, WlmT, loss_cell);

    for (int l = 0; l < LL; ++l) {
        float* xi = (l & 1) ? xb : xa;
        float* xo = (l & 1) ? xa : xb;
        qkv_attn_kernel<<<256, 512, 0, stream>>>(xi, WTs + (size_t)l*4*EE*EE);
        fc_mfma<<<dim3(4, 16), 256, 0, stream>>>(xi, WTs + (size_t)(l*4 + 3)*EE*EE,
                                                 bfc + l*EE, xo);
    }

    lm_mfma_kernel<<<dim3(VV/64, NROWS/64), 256, 0, stream>>>(xb, WlmT, blm, out, pm, pz);
    loss_kernel<<<NROWS, 128, 0, stream>>>(pm, pz, out, targets, loss_cell);
}

// Round 10
// 208.080 us; speedup vs baseline: 5.2829x; 1.1621x over previous
//
#include <hip/hip_runtime.h>

#define BB 8
#define TT 128
#define EE 256
#define VV 8192
#define LL 5
#define NROWS (BB*TT)   // 1024

typedef __attribute__((ext_vector_type(8))) short bf16x8;
typedef __attribute__((ext_vector_type(4))) float f32x4;

__device__ inline ushort f2bf(float f) {
    union { float f; unsigned u; } c; c.f = f;
    unsigned u = c.u;
    return (ushort)((u + 0x7FFF + ((u >> 16) & 1)) >> 16);  // RNE
}

// ---------------- prep: loss-cell zero + WlmT + per-layer weight transposes + embedding ----
__global__ __launch_bounds__(256) void prep_kernel(
        const int* __restrict__ idxs, const float* __restrict__ emb, const float* __restrict__ pos,
        const float* __restrict__ Wq, const float* __restrict__ Wk,
        const float* __restrict__ Wv, const float* __restrict__ Wfc,
        const float* __restrict__ Wlm,
        float* __restrict__ x0, ushort* __restrict__ WTs, ushort* __restrict__ WlmT,
        float* __restrict__ loss_cell) {
    int id = blockIdx.x;
    if (id == 0) {
        if (threadIdx.x == 0) *loss_cell = 0.f;
        return;
    }
    if (id < 513) {
        __shared__ ushort ts[64][72];
        int idw = id - 1;
        int v0 = (idw & 127) * 64, k0 = (idw >> 7) * 64;
        int lane = threadIdx.x & 63, w = threadIdx.x >> 6;
        for (int kk = w; kk < 64; kk += 4)
            ts[lane][kk] = f2bf(Wlm[(size_t)(k0 + kk)*VV + v0 + lane]);
        __syncthreads();
        for (int vv = w; vv < 64; vv += 4)
            WlmT[(size_t)(v0 + vv)*EE + k0 + lane] = ts[vv][lane];
        return;
    }
    if (id < 833) {
        __shared__ ushort ts[64][72];
        int idm = id - 513;
        int mat = idm >> 4, tile = idm & 15;
        int l = mat >> 2, type = mat & 3;
        const float* src = (type == 0 ? Wq : type == 1 ? Wk : type == 2 ? Wv : Wfc) + l*EE*EE;
        ushort* dst = WTs + mat*EE*EE;
        int i0 = (tile >> 2) * 64, o0 = (tile & 3) * 64;
        int lane = threadIdx.x & 63, w = threadIdx.x >> 6;
        for (int ii = w; ii < 64; ii += 4)
            ts[lane][ii] = f2bf(src[(i0 + ii)*EE + o0 + lane]);
        __syncthreads();
        for (int oo = w; oo < 64; oo += 4)
            dst[(o0 + oo)*EE + i0 + lane] = ts[oo][lane];
        return;
    }
    int h = threadIdx.x;
    int row0 = (id - 833) * 4;
    for (int r = 0; r < 4; ++r) {
        int row = row0 + r;
        x0[row*EE + h] = emb[(size_t)idxs[row]*EE + h] + pos[(row & (TT-1))*EE + h];
    }
}

// ---------------- fused qkv+attn: block = (batch b, 8 heads). grid 256 x 512 threads.
__global__ __launch_bounds__(512) void qkv_attn_kernel(
        float* __restrict__ x, const ushort* __restrict__ WTl) {
    __shared__ __align__(16) ushort Xs[128*256];   // 64KB swizzled bf16 x_b
    __shared__ __align__(16) ushort Bs[32*256];    // 16KB swizzled bf16 [q8|k8|v8|pad8]
    __shared__ float QS[8*132], KS[8*132], VS[8*132], MS[8*132], RV[8*132];
    int tid = threadIdx.x, lane = tid & 63, w = tid >> 6;   // 8 waves
    int b  = blockIdx.x >> 5;
    int h0 = (blockIdx.x & 31) * 8;

    // stage x_b: one row (256 f32) per wave-iter
    for (int rr = w; rr < 128; rr += 8) {
        float4 v = *(const float4*)&x[(size_t)(b*TT + rr)*EE + lane*4];
        ushort4 hh; hh.x = f2bf(v.x); hh.y = f2bf(v.y); hh.z = f2bf(v.z); hh.w = f2bf(v.w);
        *(ushort4*)&Xs[rr*256 + ((lane*4) ^ ((rr & 7) << 3))] = hh;
    }
    // stage B: 32 cols (q8|k8|v8|zero8) x K=256
    {
        int c = tid >> 4;               // 0..31
        int kb = (tid & 15) * 16;       // 0..240
        uint4 v0 = make_uint4(0,0,0,0), v1 = v0;
        if (c < 24) {
            int mat = c >> 3;           // 0=q,1=k,2=v
            int col = h0 + (c & 7);
            const ushort* src = WTl + (size_t)mat*EE*EE + (size_t)col*EE + kb;
            v0 = *(const uint4*)&src[0];
            v1 = *(const uint4*)&src[8];
        }
        *(uint4*)&Bs[c*256 + (kb ^ ((c & 7) << 3))] = v0;
        *(uint4*)&Bs[c*256 + ((kb + 8) ^ ((c & 7) << 3))] = v1;
    }
    __syncthreads();

    // qkv MFMA: wave w -> rows w*16..w*16+15, 2 col-tiles (32 cols, 24 valid)
    {
        f32x4 acc[2] = {};
        int rband = w*16 + (lane & 15);
        int kq = (lane >> 4) * 8;
        for (int ks = 0; ks < 8; ++ks) {
            int kk = ks*32 + kq;
            bf16x8 a = *(const bf16x8*)&Xs[rband*256 + (kk ^ ((rband & 7) << 3))];
            #pragma unroll
            for (int ct = 0; ct < 2; ++ct) {
                int c = ct*16 + (lane & 15);
                bf16x8 bb = *(const bf16x8*)&Bs[c*256 + (kk ^ ((c & 7) << 3))];
                acc[ct] = __builtin_amdgcn_mfma_f32_16x16x32_bf16(a, bb, acc[ct], 0, 0, 0);
            }
        }
        int r_ = w*16 + ((lane >> 4) << 2);
        #pragma unroll
        for (int ct = 0; ct < 2; ++ct) {
            int col24 = ct*16 + (lane & 15);
            #pragma unroll
            for (int j = 0; j < 4; ++j) {
                float val = acc[ct][j];
                int row = r_ + j;
                if (col24 < 8)       QS[col24*132 + row] = val;
                else if (col24 < 16) KS[(col24-8)*132 + row] = val;
                else if (col24 < 24) VS[(col24-16)*132 + row] = val;
            }
        }
    }
    __syncthreads();

    // attention: head g = wave w, 64 lanes; 2 cols/rows per lane
    int g = w, lg = lane;
    // phase 1: m_j via q-suffix-scan (rank-1 scores: m_j = k_j>=0 ? k_j*maxq : k_j*minq), then z
    {
        int j0 = lg*2;
        float k0 = KS[g*132 + j0], k1 = KS[g*132 + j0 + 1];
        float q0j = QS[g*132 + j0], q1j = QS[g*132 + j0 + 1];
        float pmax = fmaxf(q0j, q1j), pmin = fminf(q0j, q1j);
        #pragma unroll
        for (int d = 1; d < 64; d <<= 1) {
            float om = __shfl_down(pmax, d);
            float on = __shfl_down(pmin, d);
            if (lg + d < 64) { pmax = fmaxf(pmax, om); pmin = fminf(pmin, on); }
        }
        float nx = __shfl_down(pmax, 1), nn = __shfl_down(pmin, 1);
        float sp1 = (lg == 63) ? q1j : fmaxf(q1j, nx);
        float sn1 = (lg == 63) ? q1j : fminf(q1j, nn);
        float m0 = (k0 >= 0.f) ? k0*pmax : k0*pmin;
        float m1 = (k1 >= 0.f) ? k1*sp1  : k1*sn1;
        float z0 = 0.f, z1 = 0.f;
        for (int i = j0; i < TT; ++i) {
            float qi = QS[g*132 + i];
            z0 += __expf(qi*k0 - m0);
            z1 += (i >= j0+1) ? __expf(qi*k1 - m1) : 0.f;
        }
        MS[g*132 + j0]     = m0;
        MS[g*132 + j0 + 1] = m1;
        RV[g*132 + j0]     = VS[g*132 + j0] / z0;
        RV[g*132 + j0 + 1] = VS[g*132 + j0 + 1] / z1;
    }
    __syncthreads();
    // phase 2: per-row out_i = sum_{j<=i} exp(q_i k_j - m_j) * rv_j
    float a0 = 0.f, a1 = 0.f;
    {
        int i0 = lg*2;
        float q0 = QS[g*132 + i0], q1 = QS[g*132 + i0 + 1];
        for (int j = 0; j <= i0 + 1; ++j) {
            float kj = KS[g*132 + j], mj = MS[g*132 + j], rj = RV[g*132 + j];
            float e0 = __expf(q0*kj - mj) * rj;
            float e1 = __expf(q1*kj - mj) * rj;
            a0 += (j <= i0) ? e0 : 0.f;
            a1 += e1;
        }
    }
    __syncthreads();              // all phase-1/2 reads of VS done
    VS[g*132 + lg*2]     = a0;
    VS[g*132 + lg*2 + 1] = a1;
    __syncthreads();

    // coalesced RMW of x: 4 threads per row, float2 per thread (8 cols)
    {
        int row = tid >> 2, cp = (tid & 3) * 2;
        size_t gx = (size_t)(b*TT + row)*EE + h0 + cp;
        float2 xv = *(float2*)&x[gx];
        xv.x += VS[cp*132 + row];
        xv.y += VS[(cp+1)*132 + row];
        *(float2*)&x[gx] = xv;
    }
}

// ---------------- xout = xin + relu(xin @ Wfc + bfc)
__global__ __launch_bounds__(256) void fc_mfma(
        const float* __restrict__ xin, const ushort* __restrict__ WT,
        const float* __restrict__ bfc, float* __restrict__ xout) {
    __shared__ __align__(16) ushort As[64*256];
    __shared__ __align__(16) ushort Bs[64*256];
    int tid = threadIdx.x, lane = tid & 63, w = tid >> 6;
    int c0 = blockIdx.x * 64;
    int r0 = blockIdx.y * 64;

    for (int rr = w; rr < 64; rr += 4) {
        float4 v = *(const float4*)&xin[(size_t)(r0 + rr)*EE + lane*4];
        ushort4 hh; hh.x = f2bf(v.x); hh.y = f2bf(v.y); hh.z = f2bf(v.z); hh.w = f2bf(v.w);
        *(ushort4*)&As[rr*256 + ((lane*4) ^ ((rr & 7) << 3))] = hh;
    }
    for (int it = 0; it < 8; ++it) {
        int c = w*16 + (lane >> 5) + 2*it;
        int k0i = (lane & 31) * 8;
        uint4 v = *(const uint4*)&WT[(size_t)(c0 + c)*EE + k0i];
        *(uint4*)&Bs[c*256 + (k0i ^ ((c & 7) << 3))] = v;
    }
    __syncthreads();
    f32x4 acc[4] = {};
    int rband = w*16 + (lane & 15);
    int kq = (lane >> 4) * 8;
    for (int ks = 0; ks < 8; ++ks) {
        int kk = ks*32 + kq;
        bf16x8 a = *(const bf16x8*)&As[rband*256 + (kk ^ ((rband & 7) << 3))];
        #pragma unroll
        for (int n = 0; n < 4; ++n) {
            int c = n*16 + (lane & 15);
            bf16x8 b = *(const bf16x8*)&Bs[c*256 + (kk ^ ((c & 7) << 3))];
            acc[n] = __builtin_amdgcn_mfma_f32_16x16x32_bf16(a, b, acc[n], 0, 0, 0);
        }
    }
    int grow0 = r0 + w*16 + ((lane >> 4) << 2);
    #pragma unroll
    for (int n = 0; n < 4; ++n) {
        int col = c0 + n*16 + (lane & 15);
        float bias = bfc[col];
        #pragma unroll
        for (int j = 0; j < 4; ++j) {
            size_t idx = (size_t)(grow0 + j)*EE + col;
            xout[idx] = xin[idx] + fmaxf(acc[n][j] + bias, 0.f);
        }
    }
}

// ---------------- lm v4: 128x128 tile, 512 thr (8 waves, 2x4), As+Bs unified 128KB LDS
__global__ __launch_bounds__(512) void lm_mfma_kernel(
        const float* __restrict__ x, const ushort* __restrict__ WlmT,
        const float* __restrict__ blm, float* __restrict__ out,
        float* __restrict__ pm, float* __restrict__ pz) {
    __shared__ __align__(16) ushort LDSb[2*128*256];   // 128KB: As | Bs; reused as fst f32[128][132]
    ushort* As = LDSb;
    ushort* Bs = LDSb + 128*256;
    int tid = threadIdx.x;
    int lane = tid & 63, w = tid >> 6;       // 8 waves
    int c0 = blockIdx.x * 128;
    int r0 = blockIdx.y * 128;

    // stage A: 128 rows, wave w stages rows rr = w, w+8, ...
    for (int rr = w; rr < 128; rr += 8) {
        float4 v = *(const float4*)&x[(size_t)(r0 + rr)*EE + lane*4];
        ushort4 hh; hh.x = f2bf(v.x); hh.y = f2bf(v.y); hh.z = f2bf(v.z); hh.w = f2bf(v.w);
        *(ushort4*)&As[rr*256 + ((lane*4) ^ ((rr & 7) << 3))] = hh;
    }
    // stage B: 128 cols, 16 per wave (2 per wave-instr)
    for (int it = 0; it < 8; ++it) {
        int c = w*16 + (lane >> 5) + 2*it;
        int k0i = (lane & 31) * 8;
        uint4 v = *(const uint4*)&WlmT[(size_t)(c0 + c)*EE + k0i];
        *(uint4*)&Bs[c*256 + (k0i ^ ((c & 7) << 3))] = v;
    }
    __syncthreads();

    // MFMA: wave (wr=w>>2 of 2, wc=w&3 of 4): rows wr*64..+64, cols wc*32..+32
    int wr = (w >> 2) * 64, wc = (w & 3) * 32;
    f32x4 acc[4][2] = {};
    int kq = (lane >> 4) * 8;
    for (int ks = 0; ks < 8; ++ks) {
        int kk = ks*32 + kq;
        bf16x8 a[4], bfr[2];
        #pragma unroll
        for (int m = 0; m < 4; ++m) {
            int rband = wr + m*16 + (lane & 15);
            a[m] = *(const bf16x8*)&As[rband*256 + (kk ^ ((rband & 7) << 3))];
        }
        #pragma unroll
        for (int n = 0; n < 2; ++n) {
            int c = wc + n*16 + (lane & 15);
            bfr[n] = *(const bf16x8*)&Bs[c*256 + (kk ^ ((c & 7) << 3))];
        }
        #pragma unroll
        for (int m = 0; m < 4; ++m)
            #pragma unroll
            for (int n = 0; n < 2; ++n)
                acc[m][n] = __builtin_amdgcn_mfma_f32_16x16x32_bf16(a[m], bfr[n], acc[m][n], 0, 0, 0);
    }
    __syncthreads();   // done reading As/Bs; reuse as f32 staging

    float* fst = (float*)LDSb;             // [128][132] padded = 67.6KB
    float bias[2];
    #pragma unroll
    for (int n = 0; n < 2; ++n) bias[n] = blm[c0 + wc + n*16 + (lane & 15)];
    #pragma unroll
    for (int m = 0; m < 4; ++m) {
        int rw = wr + m*16 + (lane >> 4)*4;
        #pragma unroll
        for (int j = 0; j < 4; ++j) {
            int row = rw + j;
            float vals[2];
            float vmax = -INFINITY;
            #pragma unroll
            for (int n = 0; n < 2; ++n) {
                vals[n] = acc[m][n][j] + bias[n];
                fst[row*132 + wc + n*16 + (lane & 15)] = vals[n];
                vmax = fmaxf(vmax, vals[n]);
            }
            #pragma unroll
            for (int msk = 1; msk <= 8; msk <<= 1) vmax = fmaxf(vmax, __shfl_xor(vmax, msk));
            float z = 0.f;
            #pragma unroll
            for (int n = 0; n < 2; ++n) z += __expf(vals[n] - vmax);
            #pragma unroll
            for (int msk = 1; msk <= 8; msk <<= 1) z += __shfl_xor(z, msk);
            if ((lane & 15) == 0) {
                pm[(size_t)(r0 + row)*256 + blockIdx.x*4 + (w & 3)] = vmax;
                pz[(size_t)(r0 + row)*256 + blockIdx.x*4 + (w & 3)] = z;
            }
        }
    }
    __syncthreads();
    // coalesced store: 8 iters x 512 thr x float4 = 128 rows x 128 cols
    #pragma unroll
    for (int it = 0; it < 8; ++it) {
        int k = tid + it*512;
        int row = k >> 5, c4 = (k & 31)*4;
        float4 v = *(float4*)&fst[row*132 + c4];
        *(float4*)&out[(size_t)(r0 + row)*VV + c0 + c4] = v;
    }
}

// ---------------- per-row loss from 256 partials, atomicAdd mean into pre-zeroed loss cell
__global__ void loss_kernel(const float* __restrict__ pm, const float* __restrict__ pz,
                            const float* __restrict__ logits, const int* __restrict__ targets,
                            float* __restrict__ out_last) {
    int r = blockIdx.x;
    int t = threadIdx.x;             // 256
    __shared__ float sm[256], sz[256];
    float m = pm[(size_t)r*256 + t];
    float z = pz[(size_t)r*256 + t];
    sm[t] = m; __syncthreads();
    for (int s = 128; s > 0; s >>= 1) {
        if (t < s) sm[t] = fmaxf(sm[t], sm[t + s]);
        __syncthreads();
    }
    float M = sm[0];
    sz[t] = z * __expf(m - M); __syncthreads();
    for (int s = 128; s > 0; s >>= 1) {
        if (t < s) sz[t] += sz[t + s];
        __syncthreads();
    }
    if (t == 0) {
        float lse = M + logf(sz[0]);
        atomicAdd(out_last, (lse - logits[(size_t)r*VV + targets[r]]) * (1.0f / NROWS));
    }
}

extern "C" void kernel_launch(void* const* d_in, const int* in_sizes, int n_in,
                              void* d_out, int out_size, void* d_ws, size_t ws_size,
                              hipStream_t stream) {
    const int*   idxs    = (const int*)d_in[0];
    const int*   targets = (const int*)d_in[1];
    const float* emb     = (const float*)d_in[2];
    const float* pos     = (const float*)d_in[3];
    const float* Wq      = (const float*)d_in[4];
    const float* Wk      = (const float*)d_in[5];
    const float* Wv      = (const float*)d_in[6];
    const float* Wfc     = (const float*)d_in[7];
    const float* bfc     = (const float*)d_in[8];
    const float* Wlm     = (const float*)d_in[9];
    const float* blm     = (const float*)d_in[10];
    float* out = (float*)d_out;
    float* loss_cell = out + (size_t)NROWS * VV;

    float* ws = (float*)d_ws;
    float*  xa   = ws;                          // [1024,256]
    float*  xb   = xa + NROWS*EE;
    float*  pm   = xb + NROWS*EE;               // [1024,256]
    float*  pz   = pm + NROWS*256;
    ushort* WTs  = (ushort*)(pz + NROWS*256);   // 20 * 256*256 bf16
    ushort* WlmT = WTs + 20*EE*EE;              // 8192*256 bf16

    prep_kernel<<<1089, 256, 0, stream>>>(idxs, emb, pos, Wq, Wk, Wv, Wfc, Wlm,
                                          xa, WTs, WlmT, loss_cell);

    for (int l = 0; l < LL; ++l) {
        float* xi = (l & 1) ? xb : xa;
        float* xo = (l & 1) ? xa : xb;
        qkv_attn_kernel<<<256, 512, 0, stream>>>(xi, WTs + (size_t)l*4*EE*EE);
        fc_mfma<<<dim3(4, 16), 256, 0, stream>>>(xi, WTs + (size_t)(l*4 + 3)*EE*EE,
                                                 bfc + l*EE, xo);
    }

    lm_mfma_kernel<<<dim3(VV/128, NROWS/128), 512, 0, stream>>>(xb, WlmT, blm, out, pm, pz);
    loss_kernel<<<NROWS, 256, 0, stream>>>(pm, pz, out, targets, loss_cell);
}

// Round 11
// 203.406 us; speedup vs baseline: 5.4043x; 1.0230x over previous
//
#include <hip/hip_runtime.h>

#define BB 8
#define TT 128
#define EE 256
#define VV 8192
#define LL 5
#define NROWS (BB*TT)   // 1024

typedef __attribute__((ext_vector_type(8))) short bf16x8;
typedef __attribute__((ext_vector_type(4))) float f32x4;

__device__ inline ushort f2bf(float f) {
    union { float f; unsigned u; } c; c.f = f;
    unsigned u = c.u;
    return (ushort)((u + 0x7FFF + ((u >> 16) & 1)) >> 16);  // RNE
}

// ---------------- prep: loss-cell zero + WlmT + per-layer weight transposes + embedding ----
__global__ __launch_bounds__(256) void prep_kernel(
        const int* __restrict__ idxs, const float* __restrict__ emb, const float* __restrict__ pos,
        const float* __restrict__ Wq, const float* __restrict__ Wk,
        const float* __restrict__ Wv, const float* __restrict__ Wfc,
        const float* __restrict__ Wlm,
        float* __restrict__ x0, ushort* __restrict__ WTs, ushort* __restrict__ WlmT,
        float* __restrict__ loss_cell) {
    int id = blockIdx.x;
    if (id == 0) {
        if (threadIdx.x == 0) *loss_cell = 0.f;
        return;
    }
    if (id < 513) {
        __shared__ ushort ts[64][72];
        int idw = id - 1;
        int v0 = (idw & 127) * 64, k0 = (idw >> 7) * 64;
        int lane = threadIdx.x & 63, w = threadIdx.x >> 6;
        for (int kk = w; kk < 64; kk += 4)
            ts[lane][kk] = f2bf(Wlm[(size_t)(k0 + kk)*VV + v0 + lane]);
        __syncthreads();
        for (int vv = w; vv < 64; vv += 4)
            WlmT[(size_t)(v0 + vv)*EE + k0 + lane] = ts[vv][lane];
        return;
    }
    if (id < 833) {
        __shared__ ushort ts[64][72];
        int idm = id - 513;
        int mat = idm >> 4, tile = idm & 15;
        int l = mat >> 2, type = mat & 3;
        const float* src = (type == 0 ? Wq : type == 1 ? Wk : type == 2 ? Wv : Wfc) + l*EE*EE;
        ushort* dst = WTs + mat*EE*EE;
        int i0 = (tile >> 2) * 64, o0 = (tile & 3) * 64;
        int lane = threadIdx.x & 63, w = threadIdx.x >> 6;
        for (int ii = w; ii < 64; ii += 4)
            ts[lane][ii] = f2bf(src[(i0 + ii)*EE + o0 + lane]);
        __syncthreads();
        for (int oo = w; oo < 64; oo += 4)
            dst[(o0 + oo)*EE + i0 + lane] = ts[oo][lane];
        return;
    }
    int h = threadIdx.x;
    int row0 = (id - 833) * 4;
    for (int r = 0; r < 4; ++r) {
        int row = row0 + r;
        x0[row*EE + h] = emb[(size_t)idxs[row]*EE + h] + pos[(row & (TT-1))*EE + h];
    }
}

// ---------------- fused qkv+attn v3: K-split staging (61KB LDS -> 2 blocks/CU)
// block = (batch b, 8 heads). grid 256 x 512 threads.
__global__ __launch_bounds__(512, 4) void qkv_attn_kernel(
        float* __restrict__ x, const ushort* __restrict__ WTl) {
    __shared__ __align__(16) ushort Xs[128*128];   // 32KB one K-half of x_b
    __shared__ __align__(16) ushort Bs[32*128];    // 8KB one K-half of [q8|k8|v8|pad8]
    __shared__ float QS[8*132], KS[8*132], VS[8*132], MS[8*132], RV[8*132];  // 21KB
    int tid = threadIdx.x, lane = tid & 63, w = tid >> 6;   // 8 waves
    int b  = blockIdx.x >> 5;
    int h0 = (blockIdx.x & 31) * 8;

    f32x4 acc[2] = {};
    int rband = w*16 + (lane & 15);
    int kq = (lane >> 4) * 8;

    #pragma unroll
    for (int half = 0; half < 2; ++half) {
        if (half) __syncthreads();            // prior MFMA reads done before restage
        // stage x_b K-half: 2 rows per wave-instr (32 lanes x float4 = 128 cols)
        {
            int rsub = lane >> 5, cb = (lane & 31) * 4;   // cols within half
            for (int rr2 = w*2; rr2 < 128; rr2 += 16) {
                int rr = rr2 + rsub;
                float4 v = *(const float4*)&x[(size_t)(b*TT + rr)*EE + half*128 + cb];
                ushort4 hh; hh.x = f2bf(v.x); hh.y = f2bf(v.y); hh.z = f2bf(v.z); hh.w = f2bf(v.w);
                *(ushort4*)&Xs[rr*128 + (cb ^ ((rr & 7) << 3))] = hh;
            }
        }
        // stage B K-half: col c = tid>>4 (0..31), 8 ushorts at kb
        {
            int c = tid >> 4;
            int kb = (tid & 15) * 8;
            uint4 v0 = make_uint4(0,0,0,0);
            if (c < 24) {
                int mat = c >> 3;
                int col = h0 + (c & 7);
                v0 = *(const uint4*)&WTl[(size_t)mat*EE*EE + (size_t)col*EE + half*128 + kb];
            }
            *(uint4*)&Bs[c*128 + (kb ^ ((c & 7) << 3))] = v0;
        }
        __syncthreads();
        // MFMA K-half: ks 0..3
        for (int ks = 0; ks < 4; ++ks) {
            int kk = ks*32 + kq;
            bf16x8 a = *(const bf16x8*)&Xs[rband*128 + (kk ^ ((rband & 7) << 3))];
            #pragma unroll
            for (int ct = 0; ct < 2; ++ct) {
                int c = ct*16 + (lane & 15);
                bf16x8 bb = *(const bf16x8*)&Bs[c*128 + (kk ^ ((c & 7) << 3))];
                acc[ct] = __builtin_amdgcn_mfma_f32_16x16x32_bf16(a, bb, acc[ct], 0, 0, 0);
            }
        }
    }
    // scatter q|k|v to attn arrays
    {
        int r_ = w*16 + ((lane >> 4) << 2);
        #pragma unroll
        for (int ct = 0; ct < 2; ++ct) {
            int col24 = ct*16 + (lane & 15);
            #pragma unroll
            for (int j = 0; j < 4; ++j) {
                float val = acc[ct][j];
                int row = r_ + j;
                if (col24 < 8)       QS[col24*132 + row] = val;
                else if (col24 < 16) KS[(col24-8)*132 + row] = val;
                else if (col24 < 24) VS[(col24-16)*132 + row] = val;
            }
        }
    }
    __syncthreads();

    // attention: head g = wave w, 64 lanes; 2 cols/rows per lane
    int g = w, lg = lane;
    // phase 1: m_j via q-suffix-scan (rank-1 scores), then z
    {
        int j0 = lg*2;
        float k0 = KS[g*132 + j0], k1 = KS[g*132 + j0 + 1];
        float q0j = QS[g*132 + j0], q1j = QS[g*132 + j0 + 1];
        float pmax = fmaxf(q0j, q1j), pmin = fminf(q0j, q1j);
        #pragma unroll
        for (int d = 1; d < 64; d <<= 1) {
            float om = __shfl_down(pmax, d);
            float on = __shfl_down(pmin, d);
            if (lg + d < 64) { pmax = fmaxf(pmax, om); pmin = fminf(pmin, on); }
        }
        float nx = __shfl_down(pmax, 1), nn = __shfl_down(pmin, 1);
        float sp1 = (lg == 63) ? q1j : fmaxf(q1j, nx);
        float sn1 = (lg == 63) ? q1j : fminf(q1j, nn);
        float m0 = (k0 >= 0.f) ? k0*pmax : k0*pmin;
        float m1 = (k1 >= 0.f) ? k1*sp1  : k1*sn1;
        float z0 = 0.f, z1 = 0.f;
        for (int i = j0; i < TT; ++i) {
            float qi = QS[g*132 + i];
            z0 += __expf(qi*k0 - m0);
            z1 += (i >= j0+1) ? __expf(qi*k1 - m1) : 0.f;
        }
        MS[g*132 + j0]     = m0;
        MS[g*132 + j0 + 1] = m1;
        RV[g*132 + j0]     = VS[g*132 + j0] / z0;
        RV[g*132 + j0 + 1] = VS[g*132 + j0 + 1] / z1;
    }
    __syncthreads();
    // phase 2: per-row out_i = sum_{j<=i} exp(q_i k_j - m_j) * rv_j
    float a0 = 0.f, a1 = 0.f;
    {
        int i0 = lg*2;
        float q0 = QS[g*132 + i0], q1 = QS[g*132 + i0 + 1];
        for (int j = 0; j <= i0 + 1; ++j) {
            float kj = KS[g*132 + j], mj = MS[g*132 + j], rj = RV[g*132 + j];
            float e0 = __expf(q0*kj - mj) * rj;
            float e1 = __expf(q1*kj - mj) * rj;
            a0 += (j <= i0) ? e0 : 0.f;
            a1 += e1;
        }
    }
    __syncthreads();
    VS[g*132 + lg*2]     = a0;
    VS[g*132 + lg*2 + 1] = a1;
    __syncthreads();

    // coalesced RMW of x: 4 threads per row, float2 per thread
    {
        int row = tid >> 2, cp = (tid & 3) * 2;
        size_t gx = (size_t)(b*TT + row)*EE + h0 + cp;
        float2 xv = *(float2*)&x[gx];
        xv.x += VS[cp*132 + row];
        xv.y += VS[(cp+1)*132 + row];
        *(float2*)&x[gx] = xv;
    }
}

// ---------------- xout = xin + relu(xin @ Wfc + bfc)
__global__ __launch_bounds__(256) void fc_mfma(
        const float* __restrict__ xin, const ushort* __restrict__ WT,
        const float* __restrict__ bfc, float* __restrict__ xout) {
    __shared__ __align__(16) ushort As[64*256];
    __shared__ __align__(16) ushort Bs[64*256];
    int tid = threadIdx.x, lane = tid & 63, w = tid >> 6;
    int c0 = blockIdx.x * 64;
    int r0 = blockIdx.y * 64;

    for (int rr = w; rr < 64; rr += 4) {
        float4 v = *(const float4*)&xin[(size_t)(r0 + rr)*EE + lane*4];
        ushort4 hh; hh.x = f2bf(v.x); hh.y = f2bf(v.y); hh.z = f2bf(v.z); hh.w = f2bf(v.w);
        *(ushort4*)&As[rr*256 + ((lane*4) ^ ((rr & 7) << 3))] = hh;
    }
    for (int it = 0; it < 8; ++it) {
        int c = w*16 + (lane >> 5) + 2*it;
        int k0i = (lane & 31) * 8;
        uint4 v = *(const uint4*)&WT[(size_t)(c0 + c)*EE + k0i];
        *(uint4*)&Bs[c*256 + (k0i ^ ((c & 7) << 3))] = v;
    }
    __syncthreads();
    f32x4 acc[4] = {};
    int rband = w*16 + (lane & 15);
    int kq = (lane >> 4) * 8;
    for (int ks = 0; ks < 8; ++ks) {
        int kk = ks*32 + kq;
        bf16x8 a = *(const bf16x8*)&As[rband*256 + (kk ^ ((rband & 7) << 3))];
        #pragma unroll
        for (int n = 0; n < 4; ++n) {
            int c = n*16 + (lane & 15);
            bf16x8 b = *(const bf16x8*)&Bs[c*256 + (kk ^ ((c & 7) << 3))];
            acc[n] = __builtin_amdgcn_mfma_f32_16x16x32_bf16(a, b, acc[n], 0, 0, 0);
        }
    }
    int grow0 = r0 + w*16 + ((lane >> 4) << 2);
    #pragma unroll
    for (int n = 0; n < 4; ++n) {
        int col = c0 + n*16 + (lane & 15);
        float bias = bfc[col];
        #pragma unroll
        for (int j = 0; j < 4; ++j) {
            size_t idx = (size_t)(grow0 + j)*EE + col;
            xout[idx] = xin[idx] + fmaxf(acc[n][j] + bias, 0.f);
        }
    }
}

// ---------------- lm v5: 128x128 tile, K-split staging (67.6KB peak -> 2 blocks/CU)
__global__ __launch_bounds__(512, 4) void lm_mfma_kernel(
        const float* __restrict__ x, const ushort* __restrict__ WlmT,
        const float* __restrict__ blm, float* __restrict__ out,
        float* __restrict__ pm, float* __restrict__ pz) {
    __shared__ __align__(16) char LDSb[128*132*4];   // 67.6KB union
    ushort* As = (ushort*)LDSb;                      // [128][128] bf16 = 32KB
    ushort* Bs = (ushort*)LDSb + 128*128;            // [128][128] bf16 = 32KB
    float*  fst = (float*)LDSb;                      // [128][132] f32
    int tid = threadIdx.x;
    int lane = tid & 63, w = tid >> 6;       // 8 waves
    int c0 = blockIdx.x * 128;
    int r0 = blockIdx.y * 128;

    int wr = (w >> 2) * 64, wc = (w & 3) * 32;
    f32x4 acc[4][2] = {};
    int kq = (lane >> 4) * 8;

    #pragma unroll
    for (int half = 0; half < 2; ++half) {
        if (half) __syncthreads();
        // stage A K-half: 2 rows per wave-instr
        {
            int rsub = lane >> 5, cb = (lane & 31) * 4;
            for (int rr2 = w*2; rr2 < 128; rr2 += 16) {
                int rr = rr2 + rsub;
                float4 v = *(const float4*)&x[(size_t)(r0 + rr)*EE + half*128 + cb];
                ushort4 hh; hh.x = f2bf(v.x); hh.y = f2bf(v.y); hh.z = f2bf(v.z); hh.w = f2bf(v.w);
                *(ushort4*)&As[rr*128 + (cb ^ ((rr & 7) << 3))] = hh;
            }
        }
        // stage B K-half: 2 cols per wave-instr (32 lanes x 16B = one col-half)
        {
            int csub = lane >> 5, kb = (lane & 31) * 4;   // kb in ushorts (8B=4 ushorts? no)
            // each lane loads 8 bf16 (16B): 32 lanes x 8 = 256 > 128. Use 16 lanes per col.
        }
        {
            int c = tid >> 4;                 // 0..31 base, 4 col-groups of 32
            int kb = (tid & 15) * 8;          // 8 ushorts = 16B
            #pragma unroll
            for (int cg = 0; cg < 4; ++cg) {
                int cc = cg*32 + c;
                uint4 v = *(const uint4*)&WlmT[(size_t)(c0 + cc)*EE + half*128 + kb];
                *(uint4*)&Bs[cc*128 + (kb ^ ((cc & 7) << 3))] = v;
            }
        }
        __syncthreads();
        // MFMA K-half
        for (int ks = 0; ks < 4; ++ks) {
            int kk = ks*32 + kq;
            bf16x8 a[4], bfr[2];
            #pragma unroll
            for (int m = 0; m < 4; ++m) {
                int rband = wr + m*16 + (lane & 15);
                a[m] = *(const bf16x8*)&As[rband*128 + (kk ^ ((rband & 7) << 3))];
            }
            #pragma unroll
            for (int n = 0; n < 2; ++n) {
                int c = wc + n*16 + (lane & 15);
                bfr[n] = *(const bf16x8*)&Bs[c*128 + (kk ^ ((c & 7) << 3))];
            }
            #pragma unroll
            for (int m = 0; m < 4; ++m)
                #pragma unroll
                for (int n = 0; n < 2; ++n)
                    acc[m][n] = __builtin_amdgcn_mfma_f32_16x16x32_bf16(a[m], bfr[n], acc[m][n], 0, 0, 0);
        }
    }
    __syncthreads();   // done reading As/Bs; reuse as f32 staging

    float bias[2];
    #pragma unroll
    for (int n = 0; n < 2; ++n) bias[n] = blm[c0 + wc + n*16 + (lane & 15)];
    #pragma unroll
    for (int m = 0; m < 4; ++m) {
        int rw = wr + m*16 + (lane >> 4)*4;
        #pragma unroll
        for (int j = 0; j < 4; ++j) {
            int row = rw + j;
            float vals[2];
            float vmax = -INFINITY;
            #pragma unroll
            for (int n = 0; n < 2; ++n) {
                vals[n] = acc[m][n][j] + bias[n];
                fst[row*132 + wc + n*16 + (lane & 15)] = vals[n];
                vmax = fmaxf(vmax, vals[n]);
            }
            #pragma unroll
            for (int msk = 1; msk <= 8; msk <<= 1) vmax = fmaxf(vmax, __shfl_xor(vmax, msk));
            float z = 0.f;
            #pragma unroll
            for (int n = 0; n < 2; ++n) z += __expf(vals[n] - vmax);
            #pragma unroll
            for (int msk = 1; msk <= 8; msk <<= 1) z += __shfl_xor(z, msk);
            if ((lane & 15) == 0) {
                pm[(size_t)(r0 + row)*256 + blockIdx.x*4 + (w & 3)] = vmax;
                pz[(size_t)(r0 + row)*256 + blockIdx.x*4 + (w & 3)] = z;
            }
        }
    }
    __syncthreads();
    // coalesced store: 8 iters x 512 thr x float4 = 128 rows x 128 cols
    #pragma unroll
    for (int it = 0; it < 8; ++it) {
        int k = tid + it*512;
        int row = k >> 5, c4 = (k & 31)*4;
        float4 v = *(float4*)&fst[row*132 + c4];
        *(float4*)&out[(size_t)(r0 + row)*VV + c0 + c4] = v;
    }
}

// ---------------- per-row loss from 256 partials, atomicAdd mean into pre-zeroed loss cell
__global__ void loss_kernel(const float* __restrict__ pm, const float* __restrict__ pz,
                            const float* __restrict__ logits, const int* __restrict__ targets,
                            float* __restrict__ out_last) {
    int r = blockIdx.x;
    int t = threadIdx.x;             // 256
    __shared__ float sm[256], sz[256];
    float m = pm[(size_t)r*256 + t];
    float z = pz[(size_t)r*256 + t];
    sm[t] = m; __syncthreads();
    for (int s = 128; s > 0; s >>= 1) {
        if (t < s) sm[t] = fmaxf(sm[t], sm[t + s]);
        __syncthreads();
    }
    float M = sm[0];
    sz[t] = z * __expf(m - M); __syncthreads();
    for (int s = 128; s > 0; s >>= 1) {
        if (t < s) sz[t] += sz[t + s];
        __syncthreads();
    }
    if (t == 0) {
        float lse = M + logf(sz[0]);
        atomicAdd(out_last, (lse - logits[(size_t)r*VV + targets[r]]) * (1.0f / NROWS));
    }
}

extern "C" void kernel_launch(void* const* d_in, const int* in_sizes, int n_in,
                              void* d_out, int out_size, void* d_ws, size_t ws_size,
                              hipStream_t stream) {
    const int*   idxs    = (const int*)d_in[0];
    const int*   targets = (const int*)d_in[1];
    const float* emb     = (const float*)d_in[2];
    const float* pos     = (const float*)d_in[3];
    const float* Wq      = (const float*)d_in[4];
    const float* Wk      = (const float*)d_in[5];
    const float* Wv      = (const float*)d_in[6];
    const float* Wfc     = (const float*)d_in[7];
    const float* bfc     = (const float*)d_in[8];
    const float* Wlm     = (const float*)d_in[9];
    const float* blm     = (const float*)d_in[10];
    float* out = (float*)d_out;
    float* loss_cell = out + (size_t)NROWS * VV;

    float* ws = (float*)d_ws;
    float*  xa   = ws;                          // [1024,256]
    float*  xb   = xa + NROWS*EE;
    float*  pm   = xb + NROWS*EE;               // [1024,256]
    float*  pz   = pm + NROWS*256;
    ushort* WTs  = (ushort*)(pz + NROWS*256);   // 20 * 256*256 bf16
    ushort* WlmT = WTs + 20*EE*EE;              // 8192*256 bf16

    prep_kernel<<<1089, 256, 0, stream>>>(idxs, emb, pos, Wq, Wk, Wv, Wfc, Wlm,
                                          xa, WTs, WlmT, loss_cell);

    for (int l = 0; l < LL; ++l) {
        float* xi = (l & 1) ? xb : xa;
        float* xo = (l & 1) ? xa : xb;
        qkv_attn_kernel<<<256, 512, 0, stream>>>(xi, WTs + (size_t)l*4*EE*EE);
        fc_mfma<<<dim3(4, 16), 256, 0, stream>>>(xi, WTs + (size_t)(l*4 + 3)*EE*EE,
                                                 bfc + l*EE, xo);
    }

    lm_mfma_kernel<<<dim3(VV/128, NROWS/128), 512, 0, stream>>>(xb, WlmT, blm, out, pm, pz);
    loss_kernel<<<NROWS, 256, 0, stream>>>(pm, pz, out, targets, loss_cell);
}